// Round 10
// baseline (685.627 us; speedup 1.0000x reference)
//
#include <hip/hip_runtime.h>
#include <cstdint>
#include <cstddef>

#define NNODES 502
#define NKG    500
#define NPAD   512
#define NEDGE  4000
#define NET    4502   // NEDGE + NNODES self loops
#define BB     128
#define DD     1024
#define HH     256
#define MROWS  (BB*NNODES)   // 64256
#define MT     65536         // BB*NPAD padded rows
#define MCAT   628           // NKG + BB rows in hcat
#define EPITCH 136           // padded bf16 row stride (128-col epilogue transpose)
#define EP2    264           // padded bf16 row stride (256-col epilogue transpose)

typedef short short8 __attribute__((ext_vector_type(8)));
typedef float f32x4  __attribute__((ext_vector_type(4)));

__device__ __forceinline__ unsigned short f2bf(float f) {
  union { float f; unsigned int u; } v; v.f = f;
  unsigned int r = v.u + 0x7fffu + ((v.u >> 16) & 1u);
  return (unsigned short)(r >> 16);
}

__device__ __forceinline__ float bf2f(unsigned short u) {
  union { unsigned int u; float f; } v; v.u = ((unsigned int)u) << 16;
  return v.f;
}

__device__ __forceinline__ float elu(float y) {
  return (y > 0.f) ? y : (__expf(y) - 1.f);
}

// async global->LDS, 16B per lane; LDS dest = wave-uniform base + lane*16
__device__ __forceinline__ void stage16(const void* g, void* l) {
  __builtin_amdgcn_global_load_lds((__attribute__((address_space(1))) void*)g,
                                   (__attribute__((address_space(3))) void*)l, 16, 0, 0);
}

__device__ __forceinline__ void mfma16(f32x4& c, short8 a, short8 b) {
  asm volatile("v_mfma_f32_16x16x32_bf16 %0, %1, %2, %0" : "+v"(c) : "v"(a), "v"(b));
}

// ---------------- edge helpers ----------------
__device__ inline void get_edge(const int* __restrict__ e, int i, int i64mode,
                                int& src, int& dst) {
  if (i < NEDGE) {
    if (i64mode) { src = e[2*i]; dst = e[2*NEDGE + 2*i]; }
    else         { src = e[i];   dst = e[NEDGE + i]; }
  } else {
    src = dst = i - NEDGE;   // self loop
  }
  src = min(max(src, 0), NNODES-1);
  dst = min(max(dst, 0), NNODES-1);
}

// per-block int64-layout detection (uniform barriers; all threads reach)
__device__ __forceinline__ int detect_mode(const int* __restrict__ e) {
  __shared__ int sflag;
  if (threadIdx.x == 0) sflag = 0;
  __syncthreads();
  if (e[2*threadIdx.x + 1] != 0) atomicOr(&sflag, 1);
  __syncthreads();
  return sflag == 0;   // 1 => int64 layout
}

__global__ void deg_kernel(const int* __restrict__ e, int* __restrict__ deg) {
  int i64 = detect_mode(e);
  int i = blockIdx.x*256 + threadIdx.x;
  if (i >= NET) return;
  int src, dst; get_edge(e, i, i64, src, dst);
  atomicAdd(&deg[dst], 1);
}

__global__ void scan_kernel(const int* __restrict__ deg, float* __restrict__ dinv,
                            int* __restrict__ rp, int* __restrict__ cursor) {
  __shared__ int s[512];
  int t = threadIdx.x;
  int cnt = (t < NNODES) ? deg[t] : 0;
  s[t] = cnt;
  if (t < NNODES) dinv[t] = rsqrtf((float)cnt);
  __syncthreads();
  for (int off = 1; off < 512; off <<= 1) {
    int v = (t >= off) ? s[t-off] : 0;
    __syncthreads();
    s[t] += v;
    __syncthreads();
  }
  if (t == 0) rp[0] = 0;
  if (t < NNODES) { rp[t+1] = s[t]; cursor[t] = s[t] - cnt; }
}

// CSR fill (sparse aggregation path; no dense adjacency anymore)
__global__ void fill_kernel(const int* __restrict__ e, const float* __restrict__ dinv,
                            int* __restrict__ cursor, int* __restrict__ colA,
                            float* __restrict__ valA) {
  int i64 = detect_mode(e);
  int i = blockIdx.x*256 + threadIdx.x;
  if (i >= NET) return;
  int src, dst; get_edge(e, i, i64, src, dst);
  int pos = atomicAdd(&cursor[dst], 1);
  colA[pos] = src;
  valA[pos] = dinv[src] * dinv[dst];
}

// fused prep: Wt2/Wt3 (blocks 0..511), Wt1 (512..767), Xp1 (768..1407), hcat zero (1408..2035)
__global__ __launch_bounds__(256) void prep_kernel(
    const float* __restrict__ W1, const float* __restrict__ W2, const float* __restrict__ W3,
    const float* __restrict__ base, const float* __restrict__ sensor,
    unsigned short* __restrict__ Wt1, unsigned short* __restrict__ Wt2,
    unsigned short* __restrict__ Wt3, unsigned short* __restrict__ Xp1,
    float* __restrict__ hcatz) {
  int bid = blockIdx.x, tid = threadIdx.x;
  if (bid < 512) {
    const float* W = (bid & 256) ? W3 : W2;
    unsigned short* Wt = (bid & 256) ? Wt3 : Wt2;
    int n = bid & 255;
    Wt[n*HH + tid] = f2bf(W[(size_t)tid*HH + n]);
  } else if (bid < 768) {
    int n = bid - 512;
    for (int k = tid; k < DD; k += 256)
      Wt1[n*DD + k] = f2bf(W1[(size_t)k*HH + n]);
  } else if (bid < 1408) {
    int i = (bid - 768)*256 + tid;   // over 640*256, 4 elems each
    int r = i >> 8, c = (i & 255) * 4;
    float4 v = make_float4(0.f, 0.f, 0.f, 0.f);
    if (r < NKG) v = *(const float4*)&base[(size_t)r*DD + c];
    else if (r < MCAT) v = *(const float4*)&sensor[(size_t)(r-NKG)*DD + c];
    union { unsigned short u[4]; uint2 d; } p;
    p.u[0]=f2bf(v.x); p.u[1]=f2bf(v.y); p.u[2]=f2bf(v.z); p.u[3]=f2bf(v.w);
    *(uint2*)&Xp1[(size_t)r*DD + c] = p.d;
  } else {
    hcatz[(bid - 1408)*256 + tid] = 0.f;   // 628 rows
  }
}

// ---------------- layer-1 MFMA GEMM, split-K x4: hcat += Xp1*Wt1^T ----------------
__global__ __launch_bounds__(256) void gemm1m_kernel(
    const unsigned short* __restrict__ Ag,   // [640,1024]
    const unsigned short* __restrict__ Bg,   // [256,1024]
    float* __restrict__ C) {                 // [628,256] fp32 (pre-zeroed)
  __shared__ unsigned short As[128*32];
  __shared__ unsigned short Bs[128*32];
  int tid = threadIdx.x;
  int wave = tid >> 6, lane = tid & 63;
  int l15 = lane & 15, quad = lane >> 4;
  int wm = (wave & 1) * 64, wn = (wave >> 1) * 64;
  int row0 = blockIdx.y * 128, col0 = blockIdx.x * 128;
  int kbase = blockIdx.z * 256;
  f32x4 acc[4][4] = {};
  for (int k0 = kbase; k0 < kbase + 256; k0 += 32) {
#pragma unroll
    for (int q = 0; q < 2; ++q) {
      int c = wave*128 + q*64 + lane;
      stage16(Ag + (size_t)(row0 + (c>>2))*DD + k0 + (c&3)*8, As + c*8);
      stage16(Bg + (size_t)(col0 + (c>>2))*DD + k0 + (c&3)*8, Bs + c*8);
    }
    __syncthreads();
    short8 af[4], bfv[4];
#pragma unroll
    for (int i = 0; i < 4; ++i) {
      af[i]  = *(const short8*)(As + (wm + i*16 + l15)*32 + quad*8);
      bfv[i] = *(const short8*)(Bs + (wn + i*16 + l15)*32 + quad*8);
    }
#pragma unroll
    for (int mi = 0; mi < 4; ++mi)
#pragma unroll
      for (int ni = 0; ni < 4; ++ni)
        mfma16(acc[mi][ni], af[mi], bfv[ni]);
    __syncthreads();
  }
  asm volatile("s_nop 7\n\ts_nop 7" ::);
#pragma unroll
  for (int ni = 0; ni < 4; ++ni) {
    int n = col0 + wn + ni*16 + l15;
#pragma unroll
    for (int mi = 0; mi < 4; ++mi) {
      int m = row0 + wm + mi*16 + quad*4;
#pragma unroll
      for (int r = 0; r < 4; ++r)
        if (m + r < MCAT) atomicAdd(&C[(size_t)(m+r)*HH + n], acc[mi][ni][r]);
    }
  }
}

// layer-1 decomposition: A[n,h] over shared srcs, c[n] = coeff of sensor row
__global__ void ac_kernel(const int* __restrict__ rp, const int* __restrict__ colA,
                          const float* __restrict__ valA, const float* __restrict__ hcat,
                          float* __restrict__ Abuf, float* __restrict__ cbuf) {
  int n = blockIdx.x, h = threadIdx.x;
  int s = rp[n], e = rp[n+1];
  float acc = 0.f, cacc = 0.f;
  for (int t = s; t < e; ++t) {
    int cl = colA[t]; float v = valA[t];
    if (cl < NKG) acc += v * hcat[cl*HH + h];
    else if (cl == NKG) cacc += v;
  }
  Abuf[n*HH + h] = acc;
  if (h == 0) cbuf[n] = cacc;
}

// BN1 stats, stage 1: parallel partial sums. blocks 0..31: nodes; 32..39: sensor rows.
__global__ __launch_bounds__(256) void bn1n_kernel(
    const float* __restrict__ Abuf, const float* __restrict__ cbuf,
    const float* __restrict__ hcat,
    float* __restrict__ sA1, float* __restrict__ sAA1, float* __restrict__ sAc1,
    float* __restrict__ scp, float* __restrict__ ssA, float* __restrict__ sssA) {
  int bid = blockIdx.x, h = threadIdx.x;
  if (bid < 32) {
    int n0 = bid*16, n1 = min(n0+16, NNODES);
    float sA = 0, sAA = 0, sAc = 0, sc = 0, scc = 0;
    for (int n = n0; n < n1; ++n) {
      float a = Abuf[n*HH + h]; float cn = cbuf[n];
      sA += a; sAA += a*a; sAc += a*cn; sc += cn; scc += cn*cn;
    }
    atomicAdd(&sA1[h], sA); atomicAdd(&sAA1[h], sAA); atomicAdd(&sAc1[h], sAc);
    if (h == 0) { atomicAdd(&scp[0], sc); atomicAdd(&scp[1], scc); }
  } else {
    int b0 = (bid-32)*16;
    float ss = 0, sss = 0;
    for (int b = b0; b < b0+16; ++b) {
      float v = hcat[(size_t)(NKG + b)*HH + h]; ss += v; sss += v*v;
    }
    atomicAdd(&ssA[h], ss); atomicAdd(&sssA[h], sss);
  }
}

// BN1 stats, stage 2: analytic mean/var -> scale/shift
__global__ void fin1_kernel(const float* __restrict__ sA1, const float* __restrict__ sAA1,
                            const float* __restrict__ sAc1, const float* __restrict__ scp,
                            const float* __restrict__ ssA, const float* __restrict__ sssA,
                            const float* __restrict__ gamma, const float* __restrict__ beta,
                            float* __restrict__ scale, float* __restrict__ shift) {
  int h = threadIdx.x;
  float sA = sA1[h], sAA = sAA1[h], sAc = sAc1[h];
  float sc = scp[0], scc = scp[1];
  float ss = ssA[h], sss = sssA[h];
  const float cnt = (float)MROWS;
  float mean = ((float)BB * sA + sc*ss) / cnt;
  float msq  = ((float)BB * sAA + 2.f*sAc*ss + scc*sss) / cnt;
  float var  = msq - mean*mean;
  float scl  = gamma[h] * rsqrtf(var + 1e-5f);
  scale[h] = scl; shift[h] = beta[h] - mean*scl;
}

// layer-1 output -> padded bf16 Xb [MT,256]; 4 ch/thread, loop-free
__global__ __launch_bounds__(256) void x2_kernel(
    const float* __restrict__ Abuf, const float* __restrict__ cbuf,
    const float* __restrict__ hcat, const float* __restrict__ scale,
    const float* __restrict__ shift, unsigned short* __restrict__ Xb) {
  int idx = blockIdx.x*256 + threadIdx.x;   // over MT*64
  int row = idx >> 6, h0 = (idx & 63)*4;
  int b = row >> 9, n = row & (NPAD-1);
  union { unsigned short u[4]; uint2 d; } p;
  p.d = make_uint2(0,0);
  if (n < NNODES) {
    float4 a  = *(const float4*)(Abuf + n*HH + h0);
    float4 s  = *(const float4*)(hcat + (size_t)(NKG + b)*HH + h0);
    float4 sc = *(const float4*)(scale + h0);
    float4 sh = *(const float4*)(shift + h0);
    float cn = cbuf[n];
    p.u[0] = f2bf(elu((a.x + cn*s.x)*sc.x + sh.x));
    p.u[1] = f2bf(elu((a.y + cn*s.y)*sc.y + sh.y));
    p.u[2] = f2bf(elu((a.z + cn*s.z)*sc.z + sh.z));
    p.u[3] = f2bf(elu((a.w + cn*s.w)*sc.w + sh.w));
  }
  *(uint2*)(Xb + (size_t)row*HH + h0) = p.d;
}

// ---------------- MFMA GEMM-T v3: 3-buffer, 2-deep prefetch; H[m][n] row-major out ----------
// H[m][n] = sum_k A[m,k]*Wt[n,k]; 128x256 tile, BK=32, 8 K-steps, vmcnt(12) steady state.
// FBN=1: BN2 finalize inline; A reg-staged (load at t for step t+1, transform AFTER MFMA so
// the load latency hides under the MFMA cluster), ds_write into buf (t+1)%3, lgkmcnt(0).
template<int FBN>
__global__ __launch_bounds__(256) void gemmT3_kernel(
    const unsigned short* __restrict__ Ag,   // Xb [MT,256] (raw layer-2 if FBN)
    const unsigned short* __restrict__ Bg,   // Wt [256,256] (n-major)
    const float* __restrict__ sums, const float* __restrict__ ssqs,
    const float* __restrict__ gamma, const float* __restrict__ beta,
    unsigned short* __restrict__ Hout) {     // [MT, 256] row-major h
  __shared__ __align__(16) unsigned short smem[36864];  // 72KB: As 3x4096, Bs 3x8192
  __shared__ float sclL[256], shfL[256];
  unsigned short* As = smem;            // 3 bufs x [128][32]
  unsigned short* Bs = smem + 12288;    // 3 bufs x [256][32]
  int tid = threadIdx.x;
  int wave = tid >> 6, lane = tid & 63;
  int l15 = lane & 15, quad = lane >> 4;
  int wm = (wave & 1) * 64;
  int wnh = wave >> 1;                  // n-half (0:[0,128), 1:[128,256))
  int row0 = blockIdx.x * 128;
  if (FBN) {
    float mean = sums[tid] * (1.f/(float)MROWS);
    float var  = ssqs[tid] * (1.f/(float)MROWS) - mean*mean;
    float s = gamma[tid] * rsqrtf(var + 1e-5f);
    sclL[tid] = s; shfL[tid] = beta[tid] - mean*s;
    __syncthreads();
  }
  // A chunks: 2/thread; B chunks: 4/thread (per BK=32 step)
  int c0 = tid, c1 = 256 + tid;
  int r0 = c0 >> 2, o0 = (c0 & 3) * 8;
  int r1 = c1 >> 2, o1 = (c1 & 3) * 8;
  const unsigned short* A0 = Ag + (size_t)(row0 + r0)*HH + o0;
  const unsigned short* A1 = Ag + (size_t)(row0 + r1)*HH + o1;

  auto XF = [&](uint4 v, int kk) -> uint4 {
    union { unsigned short u[8]; uint4 d; } va, pa;
    va.d = v;
#pragma unroll
    for (int s = 0; s < 8; ++s)
      pa.u[s] = f2bf(elu(bf2f(va.u[s])*sclL[kk+s] + shfL[kk+s]));
    return pa.d;
  };
  auto STAGE_B = [&](int kn, int buf) {
#pragma unroll
    for (int q = 0; q < 4; ++q) {
      int c = q*256 + tid;
      int rr = c >> 2, j = (c & 3)*8;
      stage16(Bg + (size_t)rr*HH + kn + j, Bs + buf*8192 + c*8);
    }
  };

  f32x4 acc[4][8] = {};
  // ---- prologue: steps 0 and 1 into bufs 0,1 ----
  if (FBN) {
    uint4 p00 = *(const uint4*)(A0);
    uint4 p01 = *(const uint4*)(A1);
    uint4 p10 = *(const uint4*)(A0 + 32);
    uint4 p11 = *(const uint4*)(A1 + 32);
    STAGE_B(0, 0);
    STAGE_B(32, 1);
    *(uint4*)(As + c0*8)        = XF(p00, o0);
    *(uint4*)(As + c1*8)        = XF(p01, o1);
    *(uint4*)(As + 4096 + c0*8) = XF(p10, 32 + o0);
    *(uint4*)(As + 4096 + c1*8) = XF(p11, 32 + o1);
    asm volatile("s_waitcnt lgkmcnt(0)" ::: "memory");
  } else {
    stage16(A0, As + c0*8);
    stage16(A1, As + c1*8);
    STAGE_B(0, 0);
    stage16(A0 + 32, As + 4096 + c0*8);
    stage16(A1 + 32, As + 4096 + c1*8);
    STAGE_B(32, 1);
  }
  uint4 na0, na1;
#pragma unroll
  for (int t = 0; t < 8; ++t) {
    int cur = t % 3;
    int nxt2 = (t + 2) % 3;
    if (FBN) {
      if (t >= 1 && t <= 6) {         // A(t+1) -> regs (A(0),A(1) done in prologue)
        na0 = *(const uint4*)(A0 + (t+1)*32);
        na1 = *(const uint4*)(A1 + (t+1)*32);
      }
      if (t < 6) STAGE_B((t+2)*32, nxt2);
      // ledger: t=0 outstanding B(1),B(2)=8 newer than B(0); t in[1,5]: B(t+1)4+na2+B(t+2)4=10;
      // t=6: B(7)4+na2=6; t=7: need B(7) -> 0
      if (t == 0)      asm volatile("s_waitcnt vmcnt(8)"  ::: "memory");
      else if (t <= 5) asm volatile("s_waitcnt vmcnt(10)" ::: "memory");
      else if (t == 6) asm volatile("s_waitcnt vmcnt(6)"  ::: "memory");
      else             asm volatile("s_waitcnt vmcnt(0)"  ::: "memory");
    } else {
      if (t < 6) {
        stage16(A0 + (t+2)*32, As + nxt2*4096 + c0*8);
        stage16(A1 + (t+2)*32, As + nxt2*4096 + c1*8);
        STAGE_B((t+2)*32, nxt2);
        asm volatile("s_waitcnt vmcnt(12)" ::: "memory");   // retires step t's 6
      } else if (t == 6) {
        asm volatile("s_waitcnt vmcnt(6)" ::: "memory");
      } else {
        asm volatile("s_waitcnt vmcnt(0)" ::: "memory");
      }
    }
    __builtin_amdgcn_s_barrier();
    __builtin_amdgcn_sched_barrier(0);
    short8 af[4], bfv[8];
#pragma unroll
    for (int i = 0; i < 4; ++i)
      af[i] = *(const short8*)(As + cur*4096 + (wm + i*16 + l15)*32 + quad*8);
#pragma unroll
    for (int i = 0; i < 8; ++i)
      bfv[i] = *(const short8*)(Bs + cur*8192 + (wnh*128 + i*16 + l15)*32 + quad*8);
#pragma unroll
    for (int mi = 0; mi < 4; ++mi)
#pragma unroll
      for (int ni = 0; ni < 8; ++ni)
        mfma16(acc[mi][ni], af[mi], bfv[ni]);
    if (FBN && t >= 1 && t <= 6) {
      // transform A(t+1) regs (loaded this step; latency hidden under MFMA) -> buf (t+1)%3
      int nb = (t + 1) % 3;
      int kk = (t + 1) * 32;
      *(uint4*)(As + nb*4096 + c0*8) = XF(na0, kk + o0);
      *(uint4*)(As + nb*4096 + c1*8) = XF(na1, kk + o1);
      asm volatile("s_waitcnt lgkmcnt(0)" ::: "memory");
    }
    __builtin_amdgcn_sched_barrier(0);
    __builtin_amdgcn_s_barrier();
  }
  asm volatile("s_nop 7\n\ts_nop 7" ::);
  // epilogue: acc -> smem[m][n] (full 128x256, EP2 pad), then coalesced row-major writes
#pragma unroll
  for (int ni = 0; ni < 8; ++ni) {
    int nl = wnh*128 + ni*16 + l15;
#pragma unroll
    for (int mi = 0; mi < 4; ++mi) {
      int ml = wm + mi*16 + quad*4;
#pragma unroll
      for (int r = 0; r < 4; ++r)
        smem[(ml + r)*EP2 + nl] = f2bf(acc[mi][ni][r]);
    }
  }
  __syncthreads();
  int colq = (tid & 31) * 8;
  int rbase = tid >> 5;
#pragma unroll
  for (int j = 0; j < 16; ++j) {
    int row = j*8 + rbase;
    uint4 d = *(const uint4*)(smem + row*EP2 + colq);
    *(uint4*)(Hout + (size_t)(row0 + row)*HH + colq) = d;
  }
}

// ---------------- sparse CSR aggregation (replaces dense gemmS) ----------------
// Xbo[b*512+dst][c] = sum_{t in rp[dst]..rp[dst+1]} valA[t] * H[b*512+colA[t]][c]
// fp32 accumulate; BN stats from fp32 acc. Grid 1024 = 128 b x 8 dst-chunks; b = id&127
// so all 8 chunks of a batch land on one XCD (H[b] slice, 256KB, stays L2-resident).
__global__ __launch_bounds__(256) void agg_kernel(
    const int* __restrict__ rp, const int* __restrict__ colA,
    const float* __restrict__ valA, const unsigned short* __restrict__ H,
    unsigned short* __restrict__ Xbo,
    float* __restrict__ sums, float* __restrict__ ssqs) {
  __shared__ float red[512];
  int id = blockIdx.x;
  int b = id & 127, chunk = id >> 7;
  int tid = threadIdx.x;
  int dst = chunk*64 + (tid >> 2);   // 64 dsts/block, 4 threads each
  int c0 = (tid & 3) * 64;           // 64 channels/thread
  float acc[64];
#pragma unroll
  for (int j = 0; j < 64; ++j) acc[j] = 0.f;
  const unsigned short* Hb = H + (size_t)b*NPAD*HH + c0;
  if (dst < NNODES) {
    int s = rp[dst], e = rp[dst+1];
    int t = s;
    for (; t + 1 < e; t += 2) {      // 2-edge unroll for memory-level parallelism
      int s0 = colA[t], s1 = colA[t+1];
      float v0 = valA[t], v1 = valA[t+1];
      const unsigned short* r0 = Hb + (size_t)s0*HH;
      const unsigned short* r1 = Hb + (size_t)s1*HH;
      union { unsigned short u[8]; uint4 d; } w0[8], w1[8];
#pragma unroll
      for (int q = 0; q < 8; ++q) w0[q].d = *(const uint4*)(r0 + q*8);
#pragma unroll
      for (int q = 0; q < 8; ++q) w1[q].d = *(const uint4*)(r1 + q*8);
#pragma unroll
      for (int q = 0; q < 8; ++q)
#pragma unroll
        for (int j = 0; j < 8; ++j)
          acc[q*8+j] += v0 * bf2f(w0[q].u[j]) + v1 * bf2f(w1[q].u[j]);
    }
    if (t < e) {
      int s0 = colA[t]; float v0 = valA[t];
      const unsigned short* r0 = Hb + (size_t)s0*HH;
#pragma unroll
      for (int q = 0; q < 8; ++q) {
        union { unsigned short u[8]; uint4 d; } w;
        w.d = *(const uint4*)(r0 + q*8);
#pragma unroll
        for (int j = 0; j < 8; ++j)
          acc[q*8+j] += v0 * bf2f(w.u[j]);
      }
    }
    // write bf16 raw (pre-BN) output
    unsigned short* orow = Xbo + (size_t)b*NPAD*HH + (size_t)dst*HH + c0;
#pragma unroll
    for (int q = 0; q < 8; ++q) {
      union { unsigned short u[8]; uint4 d; } p;
#pragma unroll
      for (int j = 0; j < 8; ++j) p.u[j] = f2bf(acc[q*8+j]);
      *(uint4*)(orow + q*8) = p.d;
    }
  }
  // BN stat partials (only real rows contribute)
  red[tid] = 0.f; red[256 + tid] = 0.f;
  __syncthreads();
  if (dst < NNODES) {
#pragma unroll
    for (int j = 0; j < 64; ++j) {
      float v = acc[j];
      atomicAdd(&red[c0 + j], v);
      atomicAdd(&red[256 + c0 + j], v*v);
    }
  }
  __syncthreads();
  atomicAdd(&sums[tid], red[tid]);
  atomicAdd(&ssqs[tid], red[256 + tid]);
}

__global__ void finalize_kernel(const float* __restrict__ sums, const float* __restrict__ ssqs,
                                const float* __restrict__ gamma, const float* __restrict__ beta,
                                float* __restrict__ scale, float* __restrict__ shift) {
  int h = threadIdx.x;
  const float cnt = (float)MROWS;
  float mean = sums[h] / cnt;
  float var  = ssqs[h] / cnt - mean*mean;
  float scl  = gamma[h] * rsqrtf(var + 1e-5f);
  scale[h] = scl; shift[h] = beta[h] - mean*scl;
}

// final BN+ELU: read bf16 Xb (raw layer-3 pre-BN), write fp32 d_out
__global__ __launch_bounds__(256) void bnout_kernel(
    const unsigned short* __restrict__ Xb, const float* __restrict__ scale,
    const float* __restrict__ shift, float* __restrict__ O) {
  int idx = blockIdx.x*256 + threadIdx.x;   // over MT*64
  int row = idx >> 6, h0 = (idx & 63)*4;
  int b = row >> 9, n = row & (NPAD-1);
  if (n >= NNODES) return;
  union { unsigned short u[4]; uint2 d; } v;
  v.d = *(const uint2*)(Xb + (size_t)row*HH + h0);
  float4 sc = *(const float4*)(scale + h0);
  float4 sh = *(const float4*)(shift + h0);
  float4 o;
  o.x = elu(bf2f(v.u[0])*sc.x + sh.x);
  o.y = elu(bf2f(v.u[1])*sc.y + sh.y);
  o.z = elu(bf2f(v.u[2])*sc.z + sh.z);
  o.w = elu(bf2f(v.u[3])*sc.w + sh.w);
  *(float4*)(O + ((size_t)(b*NNODES + n)*HH + h0)) = o;
}

extern "C" void kernel_launch(void* const* d_in, const int* in_sizes, int n_in,
                              void* d_out, int out_size, void* d_ws, size_t ws_size,
                              hipStream_t stream) {
  const float* sensor = (const float*)d_in[0];
  const float* base   = (const float*)d_in[1];
  const int*   eidx   = (const int*)d_in[2];
  const float* W1 = (const float*)d_in[3];
  const float* g1 = (const float*)d_in[5];
  const float* be1= (const float*)d_in[6];
  const float* W2 = (const float*)d_in[7];
  const float* g2 = (const float*)d_in[9];
  const float* be2= (const float*)d_in[10];
  const float* W3 = (const float*)d_in[11];
  const float* g3 = (const float*)d_in[13];
  const float* be3= (const float*)d_in[14];

  char* ws = (char*)d_ws;
  // ---- zeroed region [0, 16384) ----
  int*   deg    = (int*)(ws + 0);
  float* sum2   = (float*)(ws + 2048);
  float* ssq2   = (float*)(ws + 3072);
  float* sum3   = (float*)(ws + 4096);
  float* ssq3   = (float*)(ws + 5120);
  float* cbuf   = (float*)(ws + 6144);
  int*   cursor = (int*)(ws + 8192);
  float* sA1    = (float*)(ws + 10496);
  float* sAA1   = (float*)(ws + 11520);
  float* sAc1   = (float*)(ws + 12544);
  float* scp    = (float*)(ws + 13568);
  float* ssA    = (float*)(ws + 13824);
  float* sssA   = (float*)(ws + 14848);
  // ---- end zeroed ----
  float* dinv   = (float*)(ws + 16384);
  int*   rp     = (int*)(ws + 18432);
  int*   colA   = (int*)(ws + 20480);
  float* valA   = (float*)(ws + 40960);
  float* scale1 = (float*)(ws + 61440);
  float* shift1 = (float*)(ws + 62464);
  float* scale3 = (float*)(ws + 65536);
  float* shift3 = (float*)(ws + 66560);
  float* Abuf   = (float*)(ws + 67584);                  // 502*256 f32
  float* hcat   = (float*)(ws + 581632);                 // 628*256 f32
  unsigned short* Wt2 = (unsigned short*)(ws + 1224704); // 256*256 bf16
  unsigned short* Wt3 = (unsigned short*)(ws + 1355776);
  unsigned short* Xb  = (unsigned short*)(ws + 2011136); // MT*256 bf16
  unsigned short* Hbuf= (unsigned short*)(ws + 35565568UL); // MT*256 bf16 (h = X*W)
  // Xp1/Wt1 alias the Hbuf region: only used before first gemmT3 writes H
  unsigned short* Xp1 = (unsigned short*)(ws + 35565568UL);            // 640*1024
  unsigned short* Wt1 = (unsigned short*)(ws + 35565568UL + 1310720);  // 256*1024
  float* out = (float*)d_out;

  hipMemsetAsync(ws, 0, 16384, stream);
  deg_kernel<<<(NET+255)/256, 256, 0, stream>>>(eidx, deg);
  scan_kernel<<<1, 512, 0, stream>>>(deg, dinv, rp, cursor);
  fill_kernel<<<(NET+255)/256, 256, 0, stream>>>(eidx, dinv, cursor, colA, valA);
  prep_kernel<<<2036, 256, 0, stream>>>(W1, W2, W3, base, sensor, Wt1, Wt2, Wt3, Xp1, hcat);

  gemm1m_kernel<<<dim3(2, 5, 4), 256, 0, stream>>>(Xp1, Wt1, hcat);
  ac_kernel<<<NNODES, 256, 0, stream>>>(rp, colA, valA, hcat, Abuf, cbuf);
  bn1n_kernel<<<40, 256, 0, stream>>>(Abuf, cbuf, hcat, sA1, sAA1, sAc1, scp, ssA, sssA);
  fin1_kernel<<<1, 256, 0, stream>>>(sA1, sAA1, sAc1, scp, ssA, sssA, g1, be1, scale1, shift1);
  x2_kernel<<<(MT*64)/256, 256, 0, stream>>>(Abuf, cbuf, hcat, scale1, shift1, Xb);

  // layer 2: dense h = Xb*W2, then sparse aggregation
  gemmT3_kernel<0><<<MT/128, 256, 0, stream>>>(Xb, Wt2, sum2, ssq2, g2, be2, Hbuf);
  agg_kernel<<<1024, 256, 0, stream>>>(rp, colA, valA, Hbuf, Xb, sum2, ssq2);
  // layer 3: BN2 finalize+apply fused into pipelined A-staging of gemmT3<1>
  gemmT3_kernel<1><<<MT/128, 256, 0, stream>>>(Xb, Wt3, sum2, ssq2, g2, be2, Hbuf);
  agg_kernel<<<1024, 256, 0, stream>>>(rp, colA, valA, Hbuf, Xb, sum3, ssq3);
  finalize_kernel<<<1, 256, 0, stream>>>(sum3, ssq3, g3, be3, scale3, shift3);
  bnout_kernel<<<(MT*64)/256, 256, 0, stream>>>(Xb, scale3, shift3, out);
}

// Round 11
// 564.399 us; speedup vs baseline: 1.2148x; 1.2148x over previous
//
#include <hip/hip_runtime.h>
#include <cstdint>
#include <cstddef>

#define NNODES 502
#define NKG    500
#define NPAD   512
#define NEDGE  4000
#define NET    4502   // NEDGE + NNODES self loops
#define BB     128
#define DD     1024
#define HH     256
#define MROWS  (BB*NNODES)   // 64256
#define MT     65536         // BB*NPAD padded rows
#define MCAT   628           // NKG + BB rows in hcat
#define EPITCH 136           // padded bf16 row stride (128-col epilogue transpose)
#define EP2    264           // padded bf16 row stride (256-col epilogue transpose)

typedef short short8 __attribute__((ext_vector_type(8)));
typedef float f32x4  __attribute__((ext_vector_type(4)));

__device__ __forceinline__ unsigned short f2bf(float f) {
  union { float f; unsigned int u; } v; v.f = f;
  unsigned int r = v.u + 0x7fffu + ((v.u >> 16) & 1u);
  return (unsigned short)(r >> 16);
}

__device__ __forceinline__ float bf2f(unsigned short u) {
  union { unsigned int u; float f; } v; v.u = ((unsigned int)u) << 16;
  return v.f;
}

__device__ __forceinline__ float elu(float y) {
  return (y > 0.f) ? y : (__expf(y) - 1.f);
}

// async global->LDS, 16B per lane; LDS dest = wave-uniform base + lane*16
__device__ __forceinline__ void stage16(const void* g, void* l) {
  __builtin_amdgcn_global_load_lds((__attribute__((address_space(1))) void*)g,
                                   (__attribute__((address_space(3))) void*)l, 16, 0, 0);
}

__device__ __forceinline__ void mfma16(f32x4& c, short8 a, short8 b) {
  asm volatile("v_mfma_f32_16x16x32_bf16 %0, %1, %2, %0" : "+v"(c) : "v"(a), "v"(b));
}

// ---------------- edge helpers ----------------
__device__ inline void get_edge(const int* __restrict__ e, int i, int i64mode,
                                int& src, int& dst) {
  if (i < NEDGE) {
    if (i64mode) { src = e[2*i]; dst = e[2*NEDGE + 2*i]; }
    else         { src = e[i];   dst = e[NEDGE + i]; }
  } else {
    src = dst = i - NEDGE;   // self loop
  }
  src = min(max(src, 0), NNODES-1);
  dst = min(max(dst, 0), NNODES-1);
}

// per-block int64-layout detection (uniform barriers; all threads reach)
__device__ __forceinline__ int detect_mode(const int* __restrict__ e) {
  __shared__ int sflag;
  if (threadIdx.x == 0) sflag = 0;
  __syncthreads();
  if (e[2*threadIdx.x + 1] != 0) atomicOr(&sflag, 1);
  __syncthreads();
  return sflag == 0;   // 1 => int64 layout
}

__global__ void deg_kernel(const int* __restrict__ e, int* __restrict__ deg) {
  int i64 = detect_mode(e);
  int i = blockIdx.x*256 + threadIdx.x;
  if (i >= NET) return;
  int src, dst; get_edge(e, i, i64, src, dst);
  atomicAdd(&deg[dst], 1);
}

__global__ void scan_kernel(const int* __restrict__ deg, float* __restrict__ dinv,
                            int* __restrict__ rp, int* __restrict__ cursor) {
  __shared__ int s[512];
  int t = threadIdx.x;
  int cnt = (t < NNODES) ? deg[t] : 0;
  s[t] = cnt;
  if (t < NNODES) dinv[t] = rsqrtf((float)cnt);
  __syncthreads();
  for (int off = 1; off < 512; off <<= 1) {
    int v = (t >= off) ? s[t-off] : 0;
    __syncthreads();
    s[t] += v;
    __syncthreads();
  }
  if (t == 0) rp[0] = 0;
  if (t < NNODES) { rp[t+1] = s[t]; cursor[t] = s[t] - cnt; }
}

// CSR fill (sparse aggregation path; no dense adjacency anymore)
__global__ void fill_kernel(const int* __restrict__ e, const float* __restrict__ dinv,
                            int* __restrict__ cursor, int* __restrict__ colA,
                            float* __restrict__ valA) {
  int i64 = detect_mode(e);
  int i = blockIdx.x*256 + threadIdx.x;
  if (i >= NET) return;
  int src, dst; get_edge(e, i, i64, src, dst);
  int pos = atomicAdd(&cursor[dst], 1);
  colA[pos] = src;
  valA[pos] = dinv[src] * dinv[dst];
}

// fused prep: Wt2/Wt3 (blocks 0..511), Wt1 (512..767), Xp1 (768..1407), hcat zero (1408..2035)
__global__ __launch_bounds__(256) void prep_kernel(
    const float* __restrict__ W1, const float* __restrict__ W2, const float* __restrict__ W3,
    const float* __restrict__ base, const float* __restrict__ sensor,
    unsigned short* __restrict__ Wt1, unsigned short* __restrict__ Wt2,
    unsigned short* __restrict__ Wt3, unsigned short* __restrict__ Xp1,
    float* __restrict__ hcatz) {
  int bid = blockIdx.x, tid = threadIdx.x;
  if (bid < 512) {
    const float* W = (bid & 256) ? W3 : W2;
    unsigned short* Wt = (bid & 256) ? Wt3 : Wt2;
    int n = bid & 255;
    Wt[n*HH + tid] = f2bf(W[(size_t)tid*HH + n]);
  } else if (bid < 768) {
    int n = bid - 512;
    for (int k = tid; k < DD; k += 256)
      Wt1[n*DD + k] = f2bf(W1[(size_t)k*HH + n]);
  } else if (bid < 1408) {
    int i = (bid - 768)*256 + tid;   // over 640*256, 4 elems each
    int r = i >> 8, c = (i & 255) * 4;
    float4 v = make_float4(0.f, 0.f, 0.f, 0.f);
    if (r < NKG) v = *(const float4*)&base[(size_t)r*DD + c];
    else if (r < MCAT) v = *(const float4*)&sensor[(size_t)(r-NKG)*DD + c];
    union { unsigned short u[4]; uint2 d; } p;
    p.u[0]=f2bf(v.x); p.u[1]=f2bf(v.y); p.u[2]=f2bf(v.z); p.u[3]=f2bf(v.w);
    *(uint2*)&Xp1[(size_t)r*DD + c] = p.d;
  } else {
    hcatz[(bid - 1408)*256 + tid] = 0.f;   // 628 rows
  }
}

// ---------------- layer-1 MFMA GEMM, split-K x4: hcat += Xp1*Wt1^T ----------------
__global__ __launch_bounds__(256) void gemm1m_kernel(
    const unsigned short* __restrict__ Ag,   // [640,1024]
    const unsigned short* __restrict__ Bg,   // [256,1024]
    float* __restrict__ C) {                 // [628,256] fp32 (pre-zeroed)
  __shared__ unsigned short As[128*32];
  __shared__ unsigned short Bs[128*32];
  int tid = threadIdx.x;
  int wave = tid >> 6, lane = tid & 63;
  int l15 = lane & 15, quad = lane >> 4;
  int wm = (wave & 1) * 64, wn = (wave >> 1) * 64;
  int row0 = blockIdx.y * 128, col0 = blockIdx.x * 128;
  int kbase = blockIdx.z * 256;
  f32x4 acc[4][4] = {};
  for (int k0 = kbase; k0 < kbase + 256; k0 += 32) {
#pragma unroll
    for (int q = 0; q < 2; ++q) {
      int c = wave*128 + q*64 + lane;
      stage16(Ag + (size_t)(row0 + (c>>2))*DD + k0 + (c&3)*8, As + c*8);
      stage16(Bg + (size_t)(col0 + (c>>2))*DD + k0 + (c&3)*8, Bs + c*8);
    }
    __syncthreads();
    short8 af[4], bfv[4];
#pragma unroll
    for (int i = 0; i < 4; ++i) {
      af[i]  = *(const short8*)(As + (wm + i*16 + l15)*32 + quad*8);
      bfv[i] = *(const short8*)(Bs + (wn + i*16 + l15)*32 + quad*8);
    }
#pragma unroll
    for (int mi = 0; mi < 4; ++mi)
#pragma unroll
      for (int ni = 0; ni < 4; ++ni)
        mfma16(acc[mi][ni], af[mi], bfv[ni]);
    __syncthreads();
  }
  asm volatile("s_nop 7\n\ts_nop 7" ::);
#pragma unroll
  for (int ni = 0; ni < 4; ++ni) {
    int n = col0 + wn + ni*16 + l15;
#pragma unroll
    for (int mi = 0; mi < 4; ++mi) {
      int m = row0 + wm + mi*16 + quad*4;
#pragma unroll
      for (int r = 0; r < 4; ++r)
        if (m + r < MCAT) atomicAdd(&C[(size_t)(m+r)*HH + n], acc[mi][ni][r]);
    }
  }
}

// layer-1 decomposition: A[n,h] over shared srcs, c[n] = coeff of sensor row
__global__ void ac_kernel(const int* __restrict__ rp, const int* __restrict__ colA,
                          const float* __restrict__ valA, const float* __restrict__ hcat,
                          float* __restrict__ Abuf, float* __restrict__ cbuf) {
  int n = blockIdx.x, h = threadIdx.x;
  int s = rp[n], e = rp[n+1];
  float acc = 0.f, cacc = 0.f;
  for (int t = s; t < e; ++t) {
    int cl = colA[t]; float v = valA[t];
    if (cl < NKG) acc += v * hcat[cl*HH + h];
    else if (cl == NKG) cacc += v;
  }
  Abuf[n*HH + h] = acc;
  if (h == 0) cbuf[n] = cacc;
}

// BN1 stats, stage 1: parallel partial sums. blocks 0..31: nodes; 32..39: sensor rows.
__global__ __launch_bounds__(256) void bn1n_kernel(
    const float* __restrict__ Abuf, const float* __restrict__ cbuf,
    const float* __restrict__ hcat,
    float* __restrict__ sA1, float* __restrict__ sAA1, float* __restrict__ sAc1,
    float* __restrict__ scp, float* __restrict__ ssA, float* __restrict__ sssA) {
  int bid = blockIdx.x, h = threadIdx.x;
  if (bid < 32) {
    int n0 = bid*16, n1 = min(n0+16, NNODES);
    float sA = 0, sAA = 0, sAc = 0, sc = 0, scc = 0;
    for (int n = n0; n < n1; ++n) {
      float a = Abuf[n*HH + h]; float cn = cbuf[n];
      sA += a; sAA += a*a; sAc += a*cn; sc += cn; scc += cn*cn;
    }
    atomicAdd(&sA1[h], sA); atomicAdd(&sAA1[h], sAA); atomicAdd(&sAc1[h], sAc);
    if (h == 0) { atomicAdd(&scp[0], sc); atomicAdd(&scp[1], scc); }
  } else {
    int b0 = (bid-32)*16;
    float ss = 0, sss = 0;
    for (int b = b0; b < b0+16; ++b) {
      float v = hcat[(size_t)(NKG + b)*HH + h]; ss += v; sss += v*v;
    }
    atomicAdd(&ssA[h], ss); atomicAdd(&sssA[h], sss);
  }
}

// BN1 stats, stage 2: analytic mean/var -> scale/shift
__global__ void fin1_kernel(const float* __restrict__ sA1, const float* __restrict__ sAA1,
                            const float* __restrict__ sAc1, const float* __restrict__ scp,
                            const float* __restrict__ ssA, const float* __restrict__ sssA,
                            const float* __restrict__ gamma, const float* __restrict__ beta,
                            float* __restrict__ scale, float* __restrict__ shift) {
  int h = threadIdx.x;
  float sA = sA1[h], sAA = sAA1[h], sAc = sAc1[h];
  float sc = scp[0], scc = scp[1];
  float ss = ssA[h], sss = sssA[h];
  const float cnt = (float)MROWS;
  float mean = ((float)BB * sA + sc*ss) / cnt;
  float msq  = ((float)BB * sAA + 2.f*sAc*ss + scc*sss) / cnt;
  float var  = msq - mean*mean;
  float scl  = gamma[h] * rsqrtf(var + 1e-5f);
  scale[h] = scl; shift[h] = beta[h] - mean*scl;
}

// layer-1 output -> padded bf16 Xb [MT,256]; 4 ch/thread, loop-free
__global__ __launch_bounds__(256) void x2_kernel(
    const float* __restrict__ Abuf, const float* __restrict__ cbuf,
    const float* __restrict__ hcat, const float* __restrict__ scale,
    const float* __restrict__ shift, unsigned short* __restrict__ Xb) {
  int idx = blockIdx.x*256 + threadIdx.x;   // over MT*64
  int row = idx >> 6, h0 = (idx & 63)*4;
  int b = row >> 9, n = row & (NPAD-1);
  union { unsigned short u[4]; uint2 d; } p;
  p.d = make_uint2(0,0);
  if (n < NNODES) {
    float4 a  = *(const float4*)(Abuf + n*HH + h0);
    float4 s  = *(const float4*)(hcat + (size_t)(NKG + b)*HH + h0);
    float4 sc = *(const float4*)(scale + h0);
    float4 sh = *(const float4*)(shift + h0);
    float cn = cbuf[n];
    p.u[0] = f2bf(elu((a.x + cn*s.x)*sc.x + sh.x));
    p.u[1] = f2bf(elu((a.y + cn*s.y)*sc.y + sh.y));
    p.u[2] = f2bf(elu((a.z + cn*s.z)*sc.z + sh.z));
    p.u[3] = f2bf(elu((a.w + cn*s.w)*sc.w + sh.w));
  }
  *(uint2*)(Xb + (size_t)row*HH + h0) = p.d;
}

// ---------------- MFMA GEMM-T v3: 3-buffer, 2-deep prefetch; H[m][n] row-major out ----------
// H[m][n] = sum_k A[m,k]*Wt[n,k]; 128x256 tile, BK=32, 8 K-steps, vmcnt(12) steady state.
// FBN=1: BN2 finalize inline; A reg-staged (load at t for step t+1, transform AFTER MFMA so
// the load latency hides under the MFMA cluster), ds_write into buf (t+1)%3, lgkmcnt(0).
template<int FBN>
__global__ __launch_bounds__(256) void gemmT3_kernel(
    const unsigned short* __restrict__ Ag,   // Xb [MT,256] (raw layer-2 if FBN)
    const unsigned short* __restrict__ Bg,   // Wt [256,256] (n-major)
    const float* __restrict__ sums, const float* __restrict__ ssqs,
    const float* __restrict__ gamma, const float* __restrict__ beta,
    unsigned short* __restrict__ Hout) {     // [MT, 256] row-major h
  __shared__ __align__(16) unsigned short smem[36864];  // 72KB: As 3x4096, Bs 3x8192
  __shared__ float sclL[256], shfL[256];
  unsigned short* As = smem;            // 3 bufs x [128][32]
  unsigned short* Bs = smem + 12288;    // 3 bufs x [256][32]
  int tid = threadIdx.x;
  int wave = tid >> 6, lane = tid & 63;
  int l15 = lane & 15, quad = lane >> 4;
  int wm = (wave & 1) * 64;
  int wnh = wave >> 1;                  // n-half (0:[0,128), 1:[128,256))
  int row0 = blockIdx.x * 128;
  if (FBN) {
    float mean = sums[tid] * (1.f/(float)MROWS);
    float var  = ssqs[tid] * (1.f/(float)MROWS) - mean*mean;
    float s = gamma[tid] * rsqrtf(var + 1e-5f);
    sclL[tid] = s; shfL[tid] = beta[tid] - mean*s;
    __syncthreads();
  }
  // A chunks: 2/thread; B chunks: 4/thread (per BK=32 step)
  int c0 = tid, c1 = 256 + tid;
  int r0 = c0 >> 2, o0 = (c0 & 3) * 8;
  int r1 = c1 >> 2, o1 = (c1 & 3) * 8;
  const unsigned short* A0 = Ag + (size_t)(row0 + r0)*HH + o0;
  const unsigned short* A1 = Ag + (size_t)(row0 + r1)*HH + o1;

  auto XF = [&](uint4 v, int kk) -> uint4 {
    union { unsigned short u[8]; uint4 d; } va, pa;
    va.d = v;
#pragma unroll
    for (int s = 0; s < 8; ++s)
      pa.u[s] = f2bf(elu(bf2f(va.u[s])*sclL[kk+s] + shfL[kk+s]));
    return pa.d;
  };
  auto STAGE_B = [&](int kn, int buf) {
#pragma unroll
    for (int q = 0; q < 4; ++q) {
      int c = q*256 + tid;
      int rr = c >> 2, j = (c & 3)*8;
      stage16(Bg + (size_t)rr*HH + kn + j, Bs + buf*8192 + c*8);
    }
  };

  f32x4 acc[4][8] = {};
  // ---- prologue: steps 0 and 1 into bufs 0,1 ----
  if (FBN) {
    uint4 p00 = *(const uint4*)(A0);
    uint4 p01 = *(const uint4*)(A1);
    uint4 p10 = *(const uint4*)(A0 + 32);
    uint4 p11 = *(const uint4*)(A1 + 32);
    STAGE_B(0, 0);
    STAGE_B(32, 1);
    *(uint4*)(As + c0*8)        = XF(p00, o0);
    *(uint4*)(As + c1*8)        = XF(p01, o1);
    *(uint4*)(As + 4096 + c0*8) = XF(p10, 32 + o0);
    *(uint4*)(As + 4096 + c1*8) = XF(p11, 32 + o1);
    asm volatile("s_waitcnt lgkmcnt(0)" ::: "memory");
  } else {
    stage16(A0, As + c0*8);
    stage16(A1, As + c1*8);
    STAGE_B(0, 0);
    stage16(A0 + 32, As + 4096 + c0*8);
    stage16(A1 + 32, As + 4096 + c1*8);
    STAGE_B(32, 1);
  }
  uint4 na0, na1;
#pragma unroll
  for (int t = 0; t < 8; ++t) {
    int cur = t % 3;
    int nxt2 = (t + 2) % 3;
    if (FBN) {
      if (t >= 1 && t <= 6) {         // A(t+1) -> regs (A(0),A(1) done in prologue)
        na0 = *(const uint4*)(A0 + (t+1)*32);
        na1 = *(const uint4*)(A1 + (t+1)*32);
      }
      if (t < 6) STAGE_B((t+2)*32, nxt2);
      // ledger: t=0 outstanding B(1),B(2)=8 newer than B(0); t in[1,5]: B(t+1)4+na2+B(t+2)4=10;
      // t=6: B(7)4+na2=6; t=7: need B(7) -> 0
      if (t == 0)      asm volatile("s_waitcnt vmcnt(8)"  ::: "memory");
      else if (t <= 5) asm volatile("s_waitcnt vmcnt(10)" ::: "memory");
      else if (t == 6) asm volatile("s_waitcnt vmcnt(6)"  ::: "memory");
      else             asm volatile("s_waitcnt vmcnt(0)"  ::: "memory");
    } else {
      if (t < 6) {
        stage16(A0 + (t+2)*32, As + nxt2*4096 + c0*8);
        stage16(A1 + (t+2)*32, As + nxt2*4096 + c1*8);
        STAGE_B((t+2)*32, nxt2);
        asm volatile("s_waitcnt vmcnt(12)" ::: "memory");   // retires step t's 6
      } else if (t == 6) {
        asm volatile("s_waitcnt vmcnt(6)" ::: "memory");
      } else {
        asm volatile("s_waitcnt vmcnt(0)" ::: "memory");
      }
    }
    __builtin_amdgcn_s_barrier();
    __builtin_amdgcn_sched_barrier(0);
    short8 af[4], bfv[8];
#pragma unroll
    for (int i = 0; i < 4; ++i)
      af[i] = *(const short8*)(As + cur*4096 + (wm + i*16 + l15)*32 + quad*8);
#pragma unroll
    for (int i = 0; i < 8; ++i)
      bfv[i] = *(const short8*)(Bs + cur*8192 + (wnh*128 + i*16 + l15)*32 + quad*8);
#pragma unroll
    for (int mi = 0; mi < 4; ++mi)
#pragma unroll
      for (int ni = 0; ni < 8; ++ni)
        mfma16(acc[mi][ni], af[mi], bfv[ni]);
    if (FBN && t >= 1 && t <= 6) {
      // transform A(t+1) regs (loaded this step; latency hidden under MFMA) -> buf (t+1)%3
      int nb = (t + 1) % 3;
      int kk = (t + 1) * 32;
      *(uint4*)(As + nb*4096 + c0*8) = XF(na0, kk + o0);
      *(uint4*)(As + nb*4096 + c1*8) = XF(na1, kk + o1);
      asm volatile("s_waitcnt lgkmcnt(0)" ::: "memory");
    }
    __builtin_amdgcn_sched_barrier(0);
    __builtin_amdgcn_s_barrier();
  }
  asm volatile("s_nop 7\n\ts_nop 7" ::);
  // epilogue: acc -> smem[m][n] (full 128x256, EP2 pad), then coalesced row-major writes
#pragma unroll
  for (int ni = 0; ni < 8; ++ni) {
    int nl = wnh*128 + ni*16 + l15;
#pragma unroll
    for (int mi = 0; mi < 4; ++mi) {
      int ml = wm + mi*16 + quad*4;
#pragma unroll
      for (int r = 0; r < 4; ++r)
        smem[(ml + r)*EP2 + nl] = f2bf(acc[mi][ni][r]);
    }
  }
  __syncthreads();
  int colq = (tid & 31) * 8;
  int rbase = tid >> 5;
#pragma unroll
  for (int j = 0; j < 16; ++j) {
    int row = j*8 + rbase;
    uint4 d = *(const uint4*)(smem + row*EP2 + colq);
    *(uint4*)(Hout + (size_t)(row0 + row)*HH + colq) = d;
  }
}

// ---------------- sparse CSR aggregation (spill-free sizing) ----------------
// Xbo[b*512+dst][c] = sum_{t in rp[dst]..rp[dst+1]} valA[t] * H[b*512+colA[t]][c]
// 8 threads/dst x 32 ch/thread -> acc[32] stays in VGPRs (round-10's 64 spilled to scratch).
// Grid 2048 = 128 b x 16 dst-chunks of 32; b = id&127 keeps each batch's 256KB H-slice
// on one XCD's L2.
__global__ __launch_bounds__(256) void agg_kernel(
    const int* __restrict__ rp, const int* __restrict__ colA,
    const float* __restrict__ valA, const unsigned short* __restrict__ H,
    unsigned short* __restrict__ Xbo,
    float* __restrict__ sums, float* __restrict__ ssqs) {
  __shared__ float red[512];
  int id = blockIdx.x;
  int b = id & 127, chunk = id >> 7;   // chunk 0..15
  int tid = threadIdx.x;
  int dst = chunk*32 + (tid >> 3);     // 32 dsts/block, 8 threads each
  int c0 = (tid & 7) * 32;             // 32 channels/thread
  float acc[32];
#pragma unroll
  for (int j = 0; j < 32; ++j) acc[j] = 0.f;
  const unsigned short* Hb = H + (size_t)b*NPAD*HH + c0;
  if (dst < NNODES) {
    int s = rp[dst], e = rp[dst+1];
    int t = s;
    for (; t + 1 < e; t += 2) {        // 2-edge unroll for memory-level parallelism
      int s0 = colA[t], s1 = colA[t+1];
      float v0 = valA[t], v1 = valA[t+1];
      const unsigned short* r0 = Hb + (size_t)s0*HH;
      const unsigned short* r1 = Hb + (size_t)s1*HH;
      union { unsigned short u[8]; uint4 d; } w0[4], w1[4];
#pragma unroll
      for (int q = 0; q < 4; ++q) w0[q].d = *(const uint4*)(r0 + q*8);
#pragma unroll
      for (int q = 0; q < 4; ++q) w1[q].d = *(const uint4*)(r1 + q*8);
#pragma unroll
      for (int q = 0; q < 4; ++q)
#pragma unroll
        for (int j = 0; j < 8; ++j)
          acc[q*8+j] += v0 * bf2f(w0[q].u[j]) + v1 * bf2f(w1[q].u[j]);
    }
    if (t < e) {
      int s0 = colA[t]; float v0 = valA[t];
      const unsigned short* r0 = Hb + (size_t)s0*HH;
#pragma unroll
      for (int q = 0; q < 4; ++q) {
        union { unsigned short u[8]; uint4 d; } w;
        w.d = *(const uint4*)(r0 + q*8);
#pragma unroll
        for (int j = 0; j < 8; ++j)
          acc[q*8+j] += v0 * bf2f(w.u[j]);
      }
    }
    // write bf16 raw (pre-BN) output
    unsigned short* orow = Xbo + (size_t)b*NPAD*HH + (size_t)dst*HH + c0;
#pragma unroll
    for (int q = 0; q < 4; ++q) {
      union { unsigned short u[8]; uint4 d; } p;
#pragma unroll
      for (int j = 0; j < 8; ++j) p.u[j] = f2bf(acc[q*8+j]);
      *(uint4*)(orow + q*8) = p.d;
    }
  }
  // BN stat partials (only real rows contribute)
  red[tid] = 0.f; red[256 + tid] = 0.f;
  __syncthreads();
  if (dst < NNODES) {
#pragma unroll
    for (int j = 0; j < 32; ++j) {
      float v = acc[j];
      atomicAdd(&red[c0 + j], v);
      atomicAdd(&red[256 + c0 + j], v*v);
    }
  }
  __syncthreads();
  atomicAdd(&sums[tid], red[tid]);
  atomicAdd(&ssqs[tid], red[256 + tid]);
}

__global__ void finalize_kernel(const float* __restrict__ sums, const float* __restrict__ ssqs,
                                const float* __restrict__ gamma, const float* __restrict__ beta,
                                float* __restrict__ scale, float* __restrict__ shift) {
  int h = threadIdx.x;
  const float cnt = (float)MROWS;
  float mean = sums[h] / cnt;
  float var  = ssqs[h] / cnt - mean*mean;
  float scl  = gamma[h] * rsqrtf(var + 1e-5f);
  scale[h] = scl; shift[h] = beta[h] - mean*scl;
}

// final BN+ELU: read bf16 Xb (raw layer-3 pre-BN), write fp32 d_out
__global__ __launch_bounds__(256) void bnout_kernel(
    const unsigned short* __restrict__ Xb, const float* __restrict__ scale,
    const float* __restrict__ shift, float* __restrict__ O) {
  int idx = blockIdx.x*256 + threadIdx.x;   // over MT*64
  int row = idx >> 6, h0 = (idx & 63)*4;
  int b = row >> 9, n = row & (NPAD-1);
  if (n >= NNODES) return;
  union { unsigned short u[4]; uint2 d; } v;
  v.d = *(const uint2*)(Xb + (size_t)row*HH + h0);
  float4 sc = *(const float4*)(scale + h0);
  float4 sh = *(const float4*)(shift + h0);
  float4 o;
  o.x = elu(bf2f(v.u[0])*sc.x + sh.x);
  o.y = elu(bf2f(v.u[1])*sc.y + sh.y);
  o.z = elu(bf2f(v.u[2])*sc.z + sh.z);
  o.w = elu(bf2f(v.u[3])*sc.w + sh.w);
  *(float4*)(O + ((size_t)(b*NNODES + n)*HH + h0)) = o;
}

extern "C" void kernel_launch(void* const* d_in, const int* in_sizes, int n_in,
                              void* d_out, int out_size, void* d_ws, size_t ws_size,
                              hipStream_t stream) {
  const float* sensor = (const float*)d_in[0];
  const float* base   = (const float*)d_in[1];
  const int*   eidx   = (const int*)d_in[2];
  const float* W1 = (const float*)d_in[3];
  const float* g1 = (const float*)d_in[5];
  const float* be1= (const float*)d_in[6];
  const float* W2 = (const float*)d_in[7];
  const float* g2 = (const float*)d_in[9];
  const float* be2= (const float*)d_in[10];
  const float* W3 = (const float*)d_in[11];
  const float* g3 = (const float*)d_in[13];
  const float* be3= (const float*)d_in[14];

  char* ws = (char*)d_ws;
  // ---- zeroed region [0, 16384) ----
  int*   deg    = (int*)(ws + 0);
  float* sum2   = (float*)(ws + 2048);
  float* ssq2   = (float*)(ws + 3072);
  float* sum3   = (float*)(ws + 4096);
  float* ssq3   = (float*)(ws + 5120);
  float* cbuf   = (float*)(ws + 6144);
  int*   cursor = (int*)(ws + 8192);
  float* sA1    = (float*)(ws + 10496);
  float* sAA1   = (float*)(ws + 11520);
  float* sAc1   = (float*)(ws + 12544);
  float* scp    = (float*)(ws + 13568);
  float* ssA    = (float*)(ws + 13824);
  float* sssA   = (float*)(ws + 14848);
  // ---- end zeroed ----
  float* dinv   = (float*)(ws + 16384);
  int*   rp     = (int*)(ws + 18432);
  int*   colA   = (int*)(ws + 20480);
  float* valA   = (float*)(ws + 40960);
  float* scale1 = (float*)(ws + 61440);
  float* shift1 = (float*)(ws + 62464);
  float* scale3 = (float*)(ws + 65536);
  float* shift3 = (float*)(ws + 66560);
  float* Abuf   = (float*)(ws + 67584);                  // 502*256 f32
  float* hcat   = (float*)(ws + 581632);                 // 628*256 f32
  unsigned short* Wt2 = (unsigned short*)(ws + 1224704); // 256*256 bf16
  unsigned short* Wt3 = (unsigned short*)(ws + 1355776);
  unsigned short* Xb  = (unsigned short*)(ws + 2011136); // MT*256 bf16
  unsigned short* Hbuf= (unsigned short*)(ws + 35565568UL); // MT*256 bf16 (h = X*W)
  // Xp1/Wt1 alias the Hbuf region: only used before first gemmT3 writes H
  unsigned short* Xp1 = (unsigned short*)(ws + 35565568UL);            // 640*1024
  unsigned short* Wt1 = (unsigned short*)(ws + 35565568UL + 1310720);  // 256*1024
  float* out = (float*)d_out;

  hipMemsetAsync(ws, 0, 16384, stream);
  deg_kernel<<<(NET+255)/256, 256, 0, stream>>>(eidx, deg);
  scan_kernel<<<1, 512, 0, stream>>>(deg, dinv, rp, cursor);
  fill_kernel<<<(NET+255)/256, 256, 0, stream>>>(eidx, dinv, cursor, colA, valA);
  prep_kernel<<<2036, 256, 0, stream>>>(W1, W2, W3, base, sensor, Wt1, Wt2, Wt3, Xp1, hcat);

  gemm1m_kernel<<<dim3(2, 5, 4), 256, 0, stream>>>(Xp1, Wt1, hcat);
  ac_kernel<<<NNODES, 256, 0, stream>>>(rp, colA, valA, hcat, Abuf, cbuf);
  bn1n_kernel<<<40, 256, 0, stream>>>(Abuf, cbuf, hcat, sA1, sAA1, sAc1, scp, ssA, sssA);
  fin1_kernel<<<1, 256, 0, stream>>>(sA1, sAA1, sAc1, scp, ssA, sssA, g1, be1, scale1, shift1);
  x2_kernel<<<(MT*64)/256, 256, 0, stream>>>(Abuf, cbuf, hcat, scale1, shift1, Xb);

  // layer 2: dense h = Xb*W2, then sparse aggregation
  gemmT3_kernel<0><<<MT/128, 256, 0, stream>>>(Xb, Wt2, sum2, ssq2, g2, be2, Hbuf);
  agg_kernel<<<2048, 256, 0, stream>>>(rp, colA, valA, Hbuf, Xb, sum2, ssq2);
  // layer 3: BN2 finalize+apply fused into pipelined A-staging of gemmT3<1>
  gemmT3_kernel<1><<<MT/128, 256, 0, stream>>>(Xb, Wt3, sum2, ssq2, g2, be2, Hbuf);
  agg_kernel<<<2048, 256, 0, stream>>>(rp, colA, valA, Hbuf, Xb, sum3, ssq3);
  finalize_kernel<<<1, 256, 0, stream>>>(sum3, ssq3, g3, be3, scale3, shift3);
  bnout_kernel<<<(MT*64)/256, 256, 0, stream>>>(Xb, scale3, shift3, out);
}

// Round 12
// 347.912 us; speedup vs baseline: 1.9707x; 1.6222x over previous
//
#include <hip/hip_runtime.h>
#include <cstdint>
#include <cstddef>

#define NNODES 502
#define NKG    500
#define NPAD   512
#define NEDGE  4000
#define NET    4502   // NEDGE + NNODES self loops
#define BB     128
#define DD     1024
#define HH     256
#define MROWS  (BB*NNODES)   // 64256
#define MT     65536         // BB*NPAD padded rows
#define MCAT   628           // NKG + BB rows in hcat
#define EPITCH 136           // padded bf16 row stride (128-col epilogue transpose)
#define EP2    264           // padded bf16 row stride (256-col epilogue transpose)

typedef short short8 __attribute__((ext_vector_type(8)));
typedef float f32x4  __attribute__((ext_vector_type(4)));

__device__ __forceinline__ unsigned short f2bf(float f) {
  union { float f; unsigned int u; } v; v.f = f;
  unsigned int r = v.u + 0x7fffu + ((v.u >> 16) & 1u);
  return (unsigned short)(r >> 16);
}

__device__ __forceinline__ float bf2f(unsigned short u) {
  union { unsigned int u; float f; } v; v.u = ((unsigned int)u) << 16;
  return v.f;
}

__device__ __forceinline__ float elu(float y) {
  return (y > 0.f) ? y : (__expf(y) - 1.f);
}

// async global->LDS, 16B per lane; LDS dest = wave-uniform base + lane*16
__device__ __forceinline__ void stage16(const void* g, void* l) {
  __builtin_amdgcn_global_load_lds((__attribute__((address_space(1))) void*)g,
                                   (__attribute__((address_space(3))) void*)l, 16, 0, 0);
}

__device__ __forceinline__ void mfma16(f32x4& c, short8 a, short8 b) {
  asm volatile("v_mfma_f32_16x16x32_bf16 %0, %1, %2, %0" : "+v"(c) : "v"(a), "v"(b));
}

// ---------------- edge helpers ----------------
__device__ inline void get_edge(const int* __restrict__ e, int i, int i64mode,
                                int& src, int& dst) {
  if (i < NEDGE) {
    if (i64mode) { src = e[2*i]; dst = e[2*NEDGE + 2*i]; }
    else         { src = e[i];   dst = e[NEDGE + i]; }
  } else {
    src = dst = i - NEDGE;   // self loop
  }
  src = min(max(src, 0), NNODES-1);
  dst = min(max(dst, 0), NNODES-1);
}

// per-block int64-layout detection (uniform barriers; all threads reach)
__device__ __forceinline__ int detect_mode(const int* __restrict__ e) {
  __shared__ int sflag;
  if (threadIdx.x == 0) sflag = 0;
  __syncthreads();
  if (e[2*threadIdx.x + 1] != 0) atomicOr(&sflag, 1);
  __syncthreads();
  return sflag == 0;   // 1 => int64 layout
}

__global__ void deg_kernel(const int* __restrict__ e, int* __restrict__ deg) {
  int i64 = detect_mode(e);
  int i = blockIdx.x*256 + threadIdx.x;
  if (i >= NET) return;
  int src, dst; get_edge(e, i, i64, src, dst);
  atomicAdd(&deg[dst], 1);
}

__global__ void scan_kernel(const int* __restrict__ deg, float* __restrict__ dinv,
                            int* __restrict__ rp, int* __restrict__ cursor) {
  __shared__ int s[512];
  int t = threadIdx.x;
  int cnt = (t < NNODES) ? deg[t] : 0;
  s[t] = cnt;
  if (t < NNODES) dinv[t] = rsqrtf((float)cnt);
  __syncthreads();
  for (int off = 1; off < 512; off <<= 1) {
    int v = (t >= off) ? s[t-off] : 0;
    __syncthreads();
    s[t] += v;
    __syncthreads();
  }
  if (t == 0) rp[0] = 0;
  if (t < NNODES) { rp[t+1] = s[t]; cursor[t] = s[t] - cnt; }
}

// CSR fill (sparse aggregation path; no dense adjacency anymore)
__global__ void fill_kernel(const int* __restrict__ e, const float* __restrict__ dinv,
                            int* __restrict__ cursor, int* __restrict__ colA,
                            float* __restrict__ valA) {
  int i64 = detect_mode(e);
  int i = blockIdx.x*256 + threadIdx.x;
  if (i >= NET) return;
  int src, dst; get_edge(e, i, i64, src, dst);
  int pos = atomicAdd(&cursor[dst], 1);
  colA[pos] = src;
  valA[pos] = dinv[src] * dinv[dst];
}

// fused prep: Wt2/Wt3 (blocks 0..511), Wt1 (512..767), Xp1 (768..1407), hcat zero (1408..2035)
__global__ __launch_bounds__(256) void prep_kernel(
    const float* __restrict__ W1, const float* __restrict__ W2, const float* __restrict__ W3,
    const float* __restrict__ base, const float* __restrict__ sensor,
    unsigned short* __restrict__ Wt1, unsigned short* __restrict__ Wt2,
    unsigned short* __restrict__ Wt3, unsigned short* __restrict__ Xp1,
    float* __restrict__ hcatz) {
  int bid = blockIdx.x, tid = threadIdx.x;
  if (bid < 512) {
    const float* W = (bid & 256) ? W3 : W2;
    unsigned short* Wt = (bid & 256) ? Wt3 : Wt2;
    int n = bid & 255;
    Wt[n*HH + tid] = f2bf(W[(size_t)tid*HH + n]);
  } else if (bid < 768) {
    int n = bid - 512;
    for (int k = tid; k < DD; k += 256)
      Wt1[n*DD + k] = f2bf(W1[(size_t)k*HH + n]);
  } else if (bid < 1408) {
    int i = (bid - 768)*256 + tid;   // over 640*256, 4 elems each
    int r = i >> 8, c = (i & 255) * 4;
    float4 v = make_float4(0.f, 0.f, 0.f, 0.f);
    if (r < NKG) v = *(const float4*)&base[(size_t)r*DD + c];
    else if (r < MCAT) v = *(const float4*)&sensor[(size_t)(r-NKG)*DD + c];
    union { unsigned short u[4]; uint2 d; } p;
    p.u[0]=f2bf(v.x); p.u[1]=f2bf(v.y); p.u[2]=f2bf(v.z); p.u[3]=f2bf(v.w);
    *(uint2*)&Xp1[(size_t)r*DD + c] = p.d;
  } else {
    hcatz[(bid - 1408)*256 + tid] = 0.f;   // 628 rows
  }
}

// ---------------- layer-1 MFMA GEMM, split-K x4: hcat += Xp1*Wt1^T ----------------
__global__ __launch_bounds__(256) void gemm1m_kernel(
    const unsigned short* __restrict__ Ag,   // [640,1024]
    const unsigned short* __restrict__ Bg,   // [256,1024]
    float* __restrict__ C) {                 // [628,256] fp32 (pre-zeroed)
  __shared__ unsigned short As[128*32];
  __shared__ unsigned short Bs[128*32];
  int tid = threadIdx.x;
  int wave = tid >> 6, lane = tid & 63;
  int l15 = lane & 15, quad = lane >> 4;
  int wm = (wave & 1) * 64, wn = (wave >> 1) * 64;
  int row0 = blockIdx.y * 128, col0 = blockIdx.x * 128;
  int kbase = blockIdx.z * 256;
  f32x4 acc[4][4] = {};
  for (int k0 = kbase; k0 < kbase + 256; k0 += 32) {
#pragma unroll
    for (int q = 0; q < 2; ++q) {
      int c = wave*128 + q*64 + lane;
      stage16(Ag + (size_t)(row0 + (c>>2))*DD + k0 + (c&3)*8, As + c*8);
      stage16(Bg + (size_t)(col0 + (c>>2))*DD + k0 + (c&3)*8, Bs + c*8);
    }
    __syncthreads();
    short8 af[4], bfv[4];
#pragma unroll
    for (int i = 0; i < 4; ++i) {
      af[i]  = *(const short8*)(As + (wm + i*16 + l15)*32 + quad*8);
      bfv[i] = *(const short8*)(Bs + (wn + i*16 + l15)*32 + quad*8);
    }
#pragma unroll
    for (int mi = 0; mi < 4; ++mi)
#pragma unroll
      for (int ni = 0; ni < 4; ++ni)
        mfma16(acc[mi][ni], af[mi], bfv[ni]);
    __syncthreads();
  }
  asm volatile("s_nop 7\n\ts_nop 7" ::);
#pragma unroll
  for (int ni = 0; ni < 4; ++ni) {
    int n = col0 + wn + ni*16 + l15;
#pragma unroll
    for (int mi = 0; mi < 4; ++mi) {
      int m = row0 + wm + mi*16 + quad*4;
#pragma unroll
      for (int r = 0; r < 4; ++r)
        if (m + r < MCAT) atomicAdd(&C[(size_t)(m+r)*HH + n], acc[mi][ni][r]);
    }
  }
}

// layer-1 decomposition: A[n,h] over shared srcs, c[n] = coeff of sensor row
__global__ void ac_kernel(const int* __restrict__ rp, const int* __restrict__ colA,
                          const float* __restrict__ valA, const float* __restrict__ hcat,
                          float* __restrict__ Abuf, float* __restrict__ cbuf) {
  int n = blockIdx.x, h = threadIdx.x;
  int s = rp[n], e = rp[n+1];
  float acc = 0.f, cacc = 0.f;
  for (int t = s; t < e; ++t) {
    int cl = colA[t]; float v = valA[t];
    if (cl < NKG) acc += v * hcat[cl*HH + h];
    else if (cl == NKG) cacc += v;
  }
  Abuf[n*HH + h] = acc;
  if (h == 0) cbuf[n] = cacc;
}

// BN1 stats, stage 1: parallel partial sums. blocks 0..31: nodes; 32..39: sensor rows.
__global__ __launch_bounds__(256) void bn1n_kernel(
    const float* __restrict__ Abuf, const float* __restrict__ cbuf,
    const float* __restrict__ hcat,
    float* __restrict__ sA1, float* __restrict__ sAA1, float* __restrict__ sAc1,
    float* __restrict__ scp, float* __restrict__ ssA, float* __restrict__ sssA) {
  int bid = blockIdx.x, h = threadIdx.x;
  if (bid < 32) {
    int n0 = bid*16, n1 = min(n0+16, NNODES);
    float sA = 0, sAA = 0, sAc = 0, sc = 0, scc = 0;
    for (int n = n0; n < n1; ++n) {
      float a = Abuf[n*HH + h]; float cn = cbuf[n];
      sA += a; sAA += a*a; sAc += a*cn; sc += cn; scc += cn*cn;
    }
    atomicAdd(&sA1[h], sA); atomicAdd(&sAA1[h], sAA); atomicAdd(&sAc1[h], sAc);
    if (h == 0) { atomicAdd(&scp[0], sc); atomicAdd(&scp[1], scc); }
  } else {
    int b0 = (bid-32)*16;
    float ss = 0, sss = 0;
    for (int b = b0; b < b0+16; ++b) {
      float v = hcat[(size_t)(NKG + b)*HH + h]; ss += v; sss += v*v;
    }
    atomicAdd(&ssA[h], ss); atomicAdd(&sssA[h], sss);
  }
}

// BN1 stats, stage 2: analytic mean/var -> scale/shift
__global__ void fin1_kernel(const float* __restrict__ sA1, const float* __restrict__ sAA1,
                            const float* __restrict__ sAc1, const float* __restrict__ scp,
                            const float* __restrict__ ssA, const float* __restrict__ sssA,
                            const float* __restrict__ gamma, const float* __restrict__ beta,
                            float* __restrict__ scale, float* __restrict__ shift) {
  int h = threadIdx.x;
  float sA = sA1[h], sAA = sAA1[h], sAc = sAc1[h];
  float sc = scp[0], scc = scp[1];
  float ss = ssA[h], sss = sssA[h];
  const float cnt = (float)MROWS;
  float mean = ((float)BB * sA + sc*ss) / cnt;
  float msq  = ((float)BB * sAA + 2.f*sAc*ss + scc*sss) / cnt;
  float var  = msq - mean*mean;
  float scl  = gamma[h] * rsqrtf(var + 1e-5f);
  scale[h] = scl; shift[h] = beta[h] - mean*scl;
}

// layer-1 output -> padded bf16 Xb [MT,256]; 4 ch/thread, loop-free
__global__ __launch_bounds__(256) void x2_kernel(
    const float* __restrict__ Abuf, const float* __restrict__ cbuf,
    const float* __restrict__ hcat, const float* __restrict__ scale,
    const float* __restrict__ shift, unsigned short* __restrict__ Xb) {
  int idx = blockIdx.x*256 + threadIdx.x;   // over MT*64
  int row = idx >> 6, h0 = (idx & 63)*4;
  int b = row >> 9, n = row & (NPAD-1);
  union { unsigned short u[4]; uint2 d; } p;
  p.d = make_uint2(0,0);
  if (n < NNODES) {
    float4 a  = *(const float4*)(Abuf + n*HH + h0);
    float4 s  = *(const float4*)(hcat + (size_t)(NKG + b)*HH + h0);
    float4 sc = *(const float4*)(scale + h0);
    float4 sh = *(const float4*)(shift + h0);
    float cn = cbuf[n];
    p.u[0] = f2bf(elu((a.x + cn*s.x)*sc.x + sh.x));
    p.u[1] = f2bf(elu((a.y + cn*s.y)*sc.y + sh.y));
    p.u[2] = f2bf(elu((a.z + cn*s.z)*sc.z + sh.z));
    p.u[3] = f2bf(elu((a.w + cn*s.w)*sc.w + sh.w));
  }
  *(uint2*)(Xb + (size_t)row*HH + h0) = p.d;
}

// ---------------- MFMA GEMM-T v3: 3-buffer, 2-deep prefetch; H[m][n] row-major out ----------
// H[m][n] = sum_k A[m,k]*Wt[n,k]; 128x256 tile, BK=32, 8 K-steps, vmcnt(12) steady state.
// FBN=1: BN2 finalize inline; A reg-staged (load at t for step t+1, transform AFTER MFMA so
// the load latency hides under the MFMA cluster), ds_write into buf (t+1)%3, lgkmcnt(0).
template<int FBN>
__global__ __launch_bounds__(256) void gemmT3_kernel(
    const unsigned short* __restrict__ Ag,   // Xb [MT,256] (raw layer-2 if FBN)
    const unsigned short* __restrict__ Bg,   // Wt [256,256] (n-major)
    const float* __restrict__ sums, const float* __restrict__ ssqs,
    const float* __restrict__ gamma, const float* __restrict__ beta,
    unsigned short* __restrict__ Hout) {     // [MT, 256] row-major h
  __shared__ __align__(16) unsigned short smem[36864];  // 72KB: As 3x4096, Bs 3x8192
  __shared__ float sclL[256], shfL[256];
  unsigned short* As = smem;            // 3 bufs x [128][32]
  unsigned short* Bs = smem + 12288;    // 3 bufs x [256][32]
  int tid = threadIdx.x;
  int wave = tid >> 6, lane = tid & 63;
  int l15 = lane & 15, quad = lane >> 4;
  int wm = (wave & 1) * 64;
  int wnh = wave >> 1;                  // n-half (0:[0,128), 1:[128,256))
  int row0 = blockIdx.x * 128;
  if (FBN) {
    float mean = sums[tid] * (1.f/(float)MROWS);
    float var  = ssqs[tid] * (1.f/(float)MROWS) - mean*mean;
    float s = gamma[tid] * rsqrtf(var + 1e-5f);
    sclL[tid] = s; shfL[tid] = beta[tid] - mean*s;
    __syncthreads();
  }
  // A chunks: 2/thread; B chunks: 4/thread (per BK=32 step)
  int c0 = tid, c1 = 256 + tid;
  int r0 = c0 >> 2, o0 = (c0 & 3) * 8;
  int r1 = c1 >> 2, o1 = (c1 & 3) * 8;
  const unsigned short* A0 = Ag + (size_t)(row0 + r0)*HH + o0;
  const unsigned short* A1 = Ag + (size_t)(row0 + r1)*HH + o1;

  auto XF = [&](uint4 v, int kk) -> uint4 {
    union { unsigned short u[8]; uint4 d; } va, pa;
    va.d = v;
#pragma unroll
    for (int s = 0; s < 8; ++s)
      pa.u[s] = f2bf(elu(bf2f(va.u[s])*sclL[kk+s] + shfL[kk+s]));
    return pa.d;
  };
  auto STAGE_B = [&](int kn, int buf) {
#pragma unroll
    for (int q = 0; q < 4; ++q) {
      int c = q*256 + tid;
      int rr = c >> 2, j = (c & 3)*8;
      stage16(Bg + (size_t)rr*HH + kn + j, Bs + buf*8192 + c*8);
    }
  };

  f32x4 acc[4][8] = {};
  // ---- prologue: steps 0 and 1 into bufs 0,1 ----
  if (FBN) {
    uint4 p00 = *(const uint4*)(A0);
    uint4 p01 = *(const uint4*)(A1);
    uint4 p10 = *(const uint4*)(A0 + 32);
    uint4 p11 = *(const uint4*)(A1 + 32);
    STAGE_B(0, 0);
    STAGE_B(32, 1);
    *(uint4*)(As + c0*8)        = XF(p00, o0);
    *(uint4*)(As + c1*8)        = XF(p01, o1);
    *(uint4*)(As + 4096 + c0*8) = XF(p10, 32 + o0);
    *(uint4*)(As + 4096 + c1*8) = XF(p11, 32 + o1);
    asm volatile("s_waitcnt lgkmcnt(0)" ::: "memory");
  } else {
    stage16(A0, As + c0*8);
    stage16(A1, As + c1*8);
    STAGE_B(0, 0);
    stage16(A0 + 32, As + 4096 + c0*8);
    stage16(A1 + 32, As + 4096 + c1*8);
    STAGE_B(32, 1);
  }
  uint4 na0, na1;
#pragma unroll
  for (int t = 0; t < 8; ++t) {
    int cur = t % 3;
    int nxt2 = (t + 2) % 3;
    if (FBN) {
      if (t >= 1 && t <= 6) {         // A(t+1) -> regs (A(0),A(1) done in prologue)
        na0 = *(const uint4*)(A0 + (t+1)*32);
        na1 = *(const uint4*)(A1 + (t+1)*32);
      }
      if (t < 6) STAGE_B((t+2)*32, nxt2);
      // ledger: t=0 outstanding B(1),B(2)=8 newer than B(0); t in[1,5]: B(t+1)4+na2+B(t+2)4=10;
      // t=6: B(7)4+na2=6; t=7: need B(7) -> 0
      if (t == 0)      asm volatile("s_waitcnt vmcnt(8)"  ::: "memory");
      else if (t <= 5) asm volatile("s_waitcnt vmcnt(10)" ::: "memory");
      else if (t == 6) asm volatile("s_waitcnt vmcnt(6)"  ::: "memory");
      else             asm volatile("s_waitcnt vmcnt(0)"  ::: "memory");
    } else {
      if (t < 6) {
        stage16(A0 + (t+2)*32, As + nxt2*4096 + c0*8);
        stage16(A1 + (t+2)*32, As + nxt2*4096 + c1*8);
        STAGE_B((t+2)*32, nxt2);
        asm volatile("s_waitcnt vmcnt(12)" ::: "memory");   // retires step t's 6
      } else if (t == 6) {
        asm volatile("s_waitcnt vmcnt(6)" ::: "memory");
      } else {
        asm volatile("s_waitcnt vmcnt(0)" ::: "memory");
      }
    }
    __builtin_amdgcn_s_barrier();
    __builtin_amdgcn_sched_barrier(0);
    short8 af[4], bfv[8];
#pragma unroll
    for (int i = 0; i < 4; ++i)
      af[i] = *(const short8*)(As + cur*4096 + (wm + i*16 + l15)*32 + quad*8);
#pragma unroll
    for (int i = 0; i < 8; ++i)
      bfv[i] = *(const short8*)(Bs + cur*8192 + (wnh*128 + i*16 + l15)*32 + quad*8);
#pragma unroll
    for (int mi = 0; mi < 4; ++mi)
#pragma unroll
      for (int ni = 0; ni < 8; ++ni)
        mfma16(acc[mi][ni], af[mi], bfv[ni]);
    if (FBN && t >= 1 && t <= 6) {
      // transform A(t+1) regs (loaded this step; latency hidden under MFMA) -> buf (t+1)%3
      int nb = (t + 1) % 3;
      int kk = (t + 1) * 32;
      *(uint4*)(As + nb*4096 + c0*8) = XF(na0, kk + o0);
      *(uint4*)(As + nb*4096 + c1*8) = XF(na1, kk + o1);
      asm volatile("s_waitcnt lgkmcnt(0)" ::: "memory");
    }
    __builtin_amdgcn_sched_barrier(0);
    __builtin_amdgcn_s_barrier();
  }
  asm volatile("s_nop 7\n\ts_nop 7" ::);
  // epilogue: acc -> smem[m][n] (full 128x256, EP2 pad), then coalesced row-major writes
#pragma unroll
  for (int ni = 0; ni < 8; ++ni) {
    int nl = wnh*128 + ni*16 + l15;
#pragma unroll
    for (int mi = 0; mi < 4; ++mi) {
      int ml = wm + mi*16 + quad*4;
#pragma unroll
      for (int r = 0; r < 4; ++r)
        smem[(ml + r)*EP2 + nl] = f2bf(acc[mi][ni][r]);
    }
  }
  __syncthreads();
  int colq = (tid & 31) * 8;
  int rbase = tid >> 5;
#pragma unroll
  for (int j = 0; j < 16; ++j) {
    int row = j*8 + rbase;
    uint4 d = *(const uint4*)(smem + row*EP2 + colq);
    *(uint4*)(Hout + (size_t)(row0 + row)*HH + colq) = d;
  }
}

// ---------------- sparse CSR aggregation v3: LDS-resident H-slice ----------------
// Grid 256 = 128 batches x 2 channel-halves; one block per CU. Phase 1: stage the
// whole [502][128] bf16 slice (128.5KB) into LDS via global_load_lds (sequential,
// coalesced). Phase 2: the random per-edge gather H[colA[t]] is a ds_read_b128
// (~15cy) instead of an HBM/L2 load (~200-900cy) -- kills the latency chain that
// sank rounds 10-11. colA/valA stay global (36KB, L2-hot).
__global__ __launch_bounds__(256) void agg3_kernel(
    const int* __restrict__ rp, const int* __restrict__ colA,
    const float* __restrict__ valA, const unsigned short* __restrict__ H,
    unsigned short* __restrict__ Xbo,
    float* __restrict__ sums, float* __restrict__ ssqs) {
  __shared__ __align__(16) unsigned short Hs[NNODES*128];  // 128512 B
  __shared__ float red[256];
  __shared__ int rpL[NNODES+1];
  int id = blockIdx.x;
  int b = id >> 1, half = id & 1;
  int tid = threadIdx.x;
  // stage H[b*512+row][half*128 ..) -> Hs[row*128], linear LDS (8032 x 16B chunks)
  const unsigned short* Hbase = H + (size_t)b*NPAD*HH + half*128;
  for (int c = tid; c < NNODES*16; c += 256) {
    int row = c >> 4, seg = c & 15;
    stage16(Hbase + (size_t)row*HH + seg*8, Hs + c*8);
  }
  for (int i = tid; i < NNODES+1; i += 256) rpL[i] = rp[i];
  red[tid] = 0.f;
  __syncthreads();   // drains vmcnt + lgkm; Hs/rpL ready
  int chg = tid & 15;          // channel octet within the half
  int dstg = tid >> 4;         // dst stride group (16)
  int cbase = chg * 8;
  float psum[8] = {0,0,0,0,0,0,0,0}, psq[8] = {0,0,0,0,0,0,0,0};
  for (int dst = dstg; dst < NNODES; dst += 16) {
    int s = rpL[dst], e = rpL[dst+1];
    float acc[8] = {0,0,0,0,0,0,0,0};
    for (int t = s; t < e; ++t) {
      int cl = colA[t]; float v = valA[t];
      union { unsigned short u[8]; uint4 d; } w;
      w.d = *(const uint4*)(Hs + cl*128 + cbase);   // ds_read_b128
#pragma unroll
      for (int j = 0; j < 8; ++j)
        acc[j] += v * bf2f(w.u[j]);
    }
    union { unsigned short u[8]; uint4 d; } p;
#pragma unroll
    for (int j = 0; j < 8; ++j) {
      float v = acc[j];
      p.u[j] = f2bf(v);
      psum[j] += v; psq[j] += v*v;
    }
    *(uint4*)(Xbo + (size_t)b*NPAD*HH + (size_t)dst*HH + half*128 + cbase) = p.d;
  }
#pragma unroll
  for (int j = 0; j < 8; ++j) {
    atomicAdd(&red[cbase + j], psum[j]);
    atomicAdd(&red[128 + cbase + j], psq[j]);
  }
  __syncthreads();
  if (tid < 128) atomicAdd(&sums[half*128 + tid], red[tid]);
  else           atomicAdd(&ssqs[half*128 + tid - 128], red[tid]);
}

__global__ void finalize_kernel(const float* __restrict__ sums, const float* __restrict__ ssqs,
                                const float* __restrict__ gamma, const float* __restrict__ beta,
                                float* __restrict__ scale, float* __restrict__ shift) {
  int h = threadIdx.x;
  const float cnt = (float)MROWS;
  float mean = sums[h] / cnt;
  float var  = ssqs[h] / cnt - mean*mean;
  float scl  = gamma[h] * rsqrtf(var + 1e-5f);
  scale[h] = scl; shift[h] = beta[h] - mean*scl;
}

// final BN+ELU: read bf16 Xb (raw layer-3 pre-BN), write fp32 d_out
__global__ __launch_bounds__(256) void bnout_kernel(
    const unsigned short* __restrict__ Xb, const float* __restrict__ scale,
    const float* __restrict__ shift, float* __restrict__ O) {
  int idx = blockIdx.x*256 + threadIdx.x;   // over MT*64
  int row = idx >> 6, h0 = (idx & 63)*4;
  int b = row >> 9, n = row & (NPAD-1);
  if (n >= NNODES) return;
  union { unsigned short u[4]; uint2 d; } v;
  v.d = *(const uint2*)(Xb + (size_t)row*HH + h0);
  float4 sc = *(const float4*)(scale + h0);
  float4 sh = *(const float4*)(shift + h0);
  float4 o;
  o.x = elu(bf2f(v.u[0])*sc.x + sh.x);
  o.y = elu(bf2f(v.u[1])*sc.y + sh.y);
  o.z = elu(bf2f(v.u[2])*sc.z + sh.z);
  o.w = elu(bf2f(v.u[3])*sc.w + sh.w);
  *(float4*)(O + ((size_t)(b*NNODES + n)*HH + h0)) = o;
}

extern "C" void kernel_launch(void* const* d_in, const int* in_sizes, int n_in,
                              void* d_out, int out_size, void* d_ws, size_t ws_size,
                              hipStream_t stream) {
  const float* sensor = (const float*)d_in[0];
  const float* base   = (const float*)d_in[1];
  const int*   eidx   = (const int*)d_in[2];
  const float* W1 = (const float*)d_in[3];
  const float* g1 = (const float*)d_in[5];
  const float* be1= (const float*)d_in[6];
  const float* W2 = (const float*)d_in[7];
  const float* g2 = (const float*)d_in[9];
  const float* be2= (const float*)d_in[10];
  const float* W3 = (const float*)d_in[11];
  const float* g3 = (const float*)d_in[13];
  const float* be3= (const float*)d_in[14];

  char* ws = (char*)d_ws;
  // ---- zeroed region [0, 16384) ----
  int*   deg    = (int*)(ws + 0);
  float* sum2   = (float*)(ws + 2048);
  float* ssq2   = (float*)(ws + 3072);
  float* sum3   = (float*)(ws + 4096);
  float* ssq3   = (float*)(ws + 5120);
  float* cbuf   = (float*)(ws + 6144);
  int*   cursor = (int*)(ws + 8192);
  float* sA1    = (float*)(ws + 10496);
  float* sAA1   = (float*)(ws + 11520);
  float* sAc1   = (float*)(ws + 12544);
  float* scp    = (float*)(ws + 13568);
  float* ssA    = (float*)(ws + 13824);
  float* sssA   = (float*)(ws + 14848);
  // ---- end zeroed ----
  float* dinv   = (float*)(ws + 16384);
  int*   rp     = (int*)(ws + 18432);
  int*   colA   = (int*)(ws + 20480);
  float* valA   = (float*)(ws + 40960);
  float* scale1 = (float*)(ws + 61440);
  float* shift1 = (float*)(ws + 62464);
  float* scale3 = (float*)(ws + 65536);
  float* shift3 = (float*)(ws + 66560);
  float* Abuf   = (float*)(ws + 67584);                  // 502*256 f32
  float* hcat   = (float*)(ws + 581632);                 // 628*256 f32
  unsigned short* Wt2 = (unsigned short*)(ws + 1224704); // 256*256 bf16
  unsigned short* Wt3 = (unsigned short*)(ws + 1355776);
  unsigned short* Xb  = (unsigned short*)(ws + 2011136); // MT*256 bf16
  unsigned short* Hbuf= (unsigned short*)(ws + 35565568UL); // MT*256 bf16 (h = X*W)
  // Xp1/Wt1 alias the Hbuf region: only used before first gemmT3 writes H
  unsigned short* Xp1 = (unsigned short*)(ws + 35565568UL);            // 640*1024
  unsigned short* Wt1 = (unsigned short*)(ws + 35565568UL + 1310720);  // 256*1024
  float* out = (float*)d_out;

  hipMemsetAsync(ws, 0, 16384, stream);
  deg_kernel<<<(NET+255)/256, 256, 0, stream>>>(eidx, deg);
  scan_kernel<<<1, 512, 0, stream>>>(deg, dinv, rp, cursor);
  fill_kernel<<<(NET+255)/256, 256, 0, stream>>>(eidx, dinv, cursor, colA, valA);
  prep_kernel<<<2036, 256, 0, stream>>>(W1, W2, W3, base, sensor, Wt1, Wt2, Wt3, Xp1, hcat);

  gemm1m_kernel<<<dim3(2, 5, 4), 256, 0, stream>>>(Xp1, Wt1, hcat);
  ac_kernel<<<NNODES, 256, 0, stream>>>(rp, colA, valA, hcat, Abuf, cbuf);
  bn1n_kernel<<<40, 256, 0, stream>>>(Abuf, cbuf, hcat, sA1, sAA1, sAc1, scp, ssA, sssA);
  fin1_kernel<<<1, 256, 0, stream>>>(sA1, sAA1, sAc1, scp, ssA, sssA, g1, be1, scale1, shift1);
  x2_kernel<<<(MT*64)/256, 256, 0, stream>>>(Abuf, cbuf, hcat, scale1, shift1, Xb);

  // layer 2: dense h = Xb*W2, then sparse aggregation (LDS-gather)
  gemmT3_kernel<0><<<MT/128, 256, 0, stream>>>(Xb, Wt2, sum2, ssq2, g2, be2, Hbuf);
  agg3_kernel<<<256, 256, 0, stream>>>(rp, colA, valA, Hbuf, Xb, sum2, ssq2);
  // layer 3: BN2 finalize+apply fused into pipelined A-staging of gemmT3<1>
  gemmT3_kernel<1><<<MT/128, 256, 0, stream>>>(Xb, Wt3, sum2, ssq2, g2, be2, Hbuf);
  agg3_kernel<<<256, 256, 0, stream>>>(rp, colA, valA, Hbuf, Xb, sum3, ssq3);
  finalize_kernel<<<1, 256, 0, stream>>>(sum3, ssq3, g3, be3, scale3, shift3);
  bnout_kernel<<<(MT*64)/256, 256, 0, stream>>>(Xb, scale3, shift3, out);
}

// Round 13
// 316.198 us; speedup vs baseline: 2.1683x; 1.1003x over previous
//
#include <hip/hip_runtime.h>
#include <cstdint>
#include <cstddef>

#define NNODES 502
#define NKG    500
#define NPAD   512
#define NEDGE  4000
#define NET    4502   // NEDGE + NNODES self loops
#define BB     128
#define DD     1024
#define HH     256
#define MROWS  (BB*NNODES)   // 64256
#define MT     65536         // BB*NPAD padded rows
#define MCAT   628           // NKG + BB rows in hcat
#define EPITCH 136           // padded bf16 row stride (128-col epilogue transpose)
#define EP2    264           // padded bf16 row stride (256-col epilogue transpose)

typedef short short8 __attribute__((ext_vector_type(8)));
typedef float f32x4  __attribute__((ext_vector_type(4)));

__device__ __forceinline__ unsigned short f2bf(float f) {
  union { float f; unsigned int u; } v; v.f = f;
  unsigned int r = v.u + 0x7fffu + ((v.u >> 16) & 1u);
  return (unsigned short)(r >> 16);
}

__device__ __forceinline__ float bf2f(unsigned short u) {
  union { unsigned int u; float f; } v; v.u = ((unsigned int)u) << 16;
  return v.f;
}

__device__ __forceinline__ float elu(float y) {
  return (y > 0.f) ? y : (__expf(y) - 1.f);
}

// async global->LDS, 16B per lane; LDS dest = wave-uniform base + lane*16
__device__ __forceinline__ void stage16(const void* g, void* l) {
  __builtin_amdgcn_global_load_lds((__attribute__((address_space(1))) void*)g,
                                   (__attribute__((address_space(3))) void*)l, 16, 0, 0);
}

__device__ __forceinline__ void mfma16(f32x4& c, short8 a, short8 b) {
  asm volatile("v_mfma_f32_16x16x32_bf16 %0, %1, %2, %0" : "+v"(c) : "v"(a), "v"(b));
}

// ---------------- edge helpers ----------------
__device__ inline void get_edge(const int* __restrict__ e, int i, int i64mode,
                                int& src, int& dst) {
  if (i < NEDGE) {
    if (i64mode) { src = e[2*i]; dst = e[2*NEDGE + 2*i]; }
    else         { src = e[i];   dst = e[NEDGE + i]; }
  } else {
    src = dst = i - NEDGE;   // self loop
  }
  src = min(max(src, 0), NNODES-1);
  dst = min(max(dst, 0), NNODES-1);
}

// per-block int64-layout detection (uniform barriers; all threads reach)
__device__ __forceinline__ int detect_mode(const int* __restrict__ e) {
  __shared__ int sflag;
  if (threadIdx.x == 0) sflag = 0;
  __syncthreads();
  if (e[2*threadIdx.x + 1] != 0) atomicOr(&sflag, 1);
  __syncthreads();
  return sflag == 0;   // 1 => int64 layout
}

__global__ void deg_kernel(const int* __restrict__ e, int* __restrict__ deg) {
  int i64 = detect_mode(e);
  int i = blockIdx.x*256 + threadIdx.x;
  if (i >= NET) return;
  int src, dst; get_edge(e, i, i64, src, dst);
  atomicAdd(&deg[dst], 1);
}

__global__ void scan_kernel(const int* __restrict__ deg, float* __restrict__ dinv,
                            int* __restrict__ rp, int* __restrict__ cursor) {
  __shared__ int s[512];
  int t = threadIdx.x;
  int cnt = (t < NNODES) ? deg[t] : 0;
  s[t] = cnt;
  if (t < NNODES) dinv[t] = rsqrtf((float)cnt);
  __syncthreads();
  for (int off = 1; off < 512; off <<= 1) {
    int v = (t >= off) ? s[t-off] : 0;
    __syncthreads();
    s[t] += v;
    __syncthreads();
  }
  if (t == 0) rp[0] = 0;
  if (t < NNODES) { rp[t+1] = s[t]; cursor[t] = s[t] - cnt; }
}

// CSR fill (sparse aggregation path; no dense adjacency anymore)
__global__ void fill_kernel(const int* __restrict__ e, const float* __restrict__ dinv,
                            int* __restrict__ cursor, int* __restrict__ colA,
                            float* __restrict__ valA) {
  int i64 = detect_mode(e);
  int i = blockIdx.x*256 + threadIdx.x;
  if (i >= NET) return;
  int src, dst; get_edge(e, i, i64, src, dst);
  int pos = atomicAdd(&cursor[dst], 1);
  colA[pos] = src;
  valA[pos] = dinv[src] * dinv[dst];
}

// fused prep: Wt2/Wt3 (blocks 0..511), Wt1 (512..767), Xp1 (768..1407), hcat zero (1408..2035)
__global__ __launch_bounds__(256) void prep_kernel(
    const float* __restrict__ W1, const float* __restrict__ W2, const float* __restrict__ W3,
    const float* __restrict__ base, const float* __restrict__ sensor,
    unsigned short* __restrict__ Wt1, unsigned short* __restrict__ Wt2,
    unsigned short* __restrict__ Wt3, unsigned short* __restrict__ Xp1,
    float* __restrict__ hcatz) {
  int bid = blockIdx.x, tid = threadIdx.x;
  if (bid < 512) {
    const float* W = (bid & 256) ? W3 : W2;
    unsigned short* Wt = (bid & 256) ? Wt3 : Wt2;
    int n = bid & 255;
    Wt[n*HH + tid] = f2bf(W[(size_t)tid*HH + n]);
  } else if (bid < 768) {
    int n = bid - 512;
    for (int k = tid; k < DD; k += 256)
      Wt1[n*DD + k] = f2bf(W1[(size_t)k*HH + n]);
  } else if (bid < 1408) {
    int i = (bid - 768)*256 + tid;   // over 640*256, 4 elems each
    int r = i >> 8, c = (i & 255) * 4;
    float4 v = make_float4(0.f, 0.f, 0.f, 0.f);
    if (r < NKG) v = *(const float4*)&base[(size_t)r*DD + c];
    else if (r < MCAT) v = *(const float4*)&sensor[(size_t)(r-NKG)*DD + c];
    union { unsigned short u[4]; uint2 d; } p;
    p.u[0]=f2bf(v.x); p.u[1]=f2bf(v.y); p.u[2]=f2bf(v.z); p.u[3]=f2bf(v.w);
    *(uint2*)&Xp1[(size_t)r*DD + c] = p.d;
  } else {
    hcatz[(bid - 1408)*256 + tid] = 0.f;   // 628 rows
  }
}

// ---------------- layer-1 MFMA GEMM, split-K x4: hcat += Xp1*Wt1^T ----------------
__global__ __launch_bounds__(256) void gemm1m_kernel(
    const unsigned short* __restrict__ Ag,   // [640,1024]
    const unsigned short* __restrict__ Bg,   // [256,1024]
    float* __restrict__ C) {                 // [628,256] fp32 (pre-zeroed)
  __shared__ unsigned short As[128*32];
  __shared__ unsigned short Bs[128*32];
  int tid = threadIdx.x;
  int wave = tid >> 6, lane = tid & 63;
  int l15 = lane & 15, quad = lane >> 4;
  int wm = (wave & 1) * 64, wn = (wave >> 1) * 64;
  int row0 = blockIdx.y * 128, col0 = blockIdx.x * 128;
  int kbase = blockIdx.z * 256;
  f32x4 acc[4][4] = {};
  for (int k0 = kbase; k0 < kbase + 256; k0 += 32) {
#pragma unroll
    for (int q = 0; q < 2; ++q) {
      int c = wave*128 + q*64 + lane;
      stage16(Ag + (size_t)(row0 + (c>>2))*DD + k0 + (c&3)*8, As + c*8);
      stage16(Bg + (size_t)(col0 + (c>>2))*DD + k0 + (c&3)*8, Bs + c*8);
    }
    __syncthreads();
    short8 af[4], bfv[4];
#pragma unroll
    for (int i = 0; i < 4; ++i) {
      af[i]  = *(const short8*)(As + (wm + i*16 + l15)*32 + quad*8);
      bfv[i] = *(const short8*)(Bs + (wn + i*16 + l15)*32 + quad*8);
    }
#pragma unroll
    for (int mi = 0; mi < 4; ++mi)
#pragma unroll
      for (int ni = 0; ni < 4; ++ni)
        mfma16(acc[mi][ni], af[mi], bfv[ni]);
    __syncthreads();
  }
  asm volatile("s_nop 7\n\ts_nop 7" ::);
#pragma unroll
  for (int ni = 0; ni < 4; ++ni) {
    int n = col0 + wn + ni*16 + l15;
#pragma unroll
    for (int mi = 0; mi < 4; ++mi) {
      int m = row0 + wm + mi*16 + quad*4;
#pragma unroll
      for (int r = 0; r < 4; ++r)
        if (m + r < MCAT) atomicAdd(&C[(size_t)(m+r)*HH + n], acc[mi][ni][r]);
    }
  }
}

// layer-1 decomposition: A[n,h] over shared srcs, c[n] = coeff of sensor row
__global__ void ac_kernel(const int* __restrict__ rp, const int* __restrict__ colA,
                          const float* __restrict__ valA, const float* __restrict__ hcat,
                          float* __restrict__ Abuf, float* __restrict__ cbuf) {
  int n = blockIdx.x, h = threadIdx.x;
  int s = rp[n], e = rp[n+1];
  float acc = 0.f, cacc = 0.f;
  for (int t = s; t < e; ++t) {
    int cl = colA[t]; float v = valA[t];
    if (cl < NKG) acc += v * hcat[cl*HH + h];
    else if (cl == NKG) cacc += v;
  }
  Abuf[n*HH + h] = acc;
  if (h == 0) cbuf[n] = cacc;
}

// BN1 stats, stage 1: parallel partial sums. blocks 0..31: nodes; 32..39: sensor rows.
__global__ __launch_bounds__(256) void bn1n_kernel(
    const float* __restrict__ Abuf, const float* __restrict__ cbuf,
    const float* __restrict__ hcat,
    float* __restrict__ sA1, float* __restrict__ sAA1, float* __restrict__ sAc1,
    float* __restrict__ scp, float* __restrict__ ssA, float* __restrict__ sssA) {
  int bid = blockIdx.x, h = threadIdx.x;
  if (bid < 32) {
    int n0 = bid*16, n1 = min(n0+16, NNODES);
    float sA = 0, sAA = 0, sAc = 0, sc = 0, scc = 0;
    for (int n = n0; n < n1; ++n) {
      float a = Abuf[n*HH + h]; float cn = cbuf[n];
      sA += a; sAA += a*a; sAc += a*cn; sc += cn; scc += cn*cn;
    }
    atomicAdd(&sA1[h], sA); atomicAdd(&sAA1[h], sAA); atomicAdd(&sAc1[h], sAc);
    if (h == 0) { atomicAdd(&scp[0], sc); atomicAdd(&scp[1], scc); }
  } else {
    int b0 = (bid-32)*16;
    float ss = 0, sss = 0;
    for (int b = b0; b < b0+16; ++b) {
      float v = hcat[(size_t)(NKG + b)*HH + h]; ss += v; sss += v*v;
    }
    atomicAdd(&ssA[h], ss); atomicAdd(&sssA[h], sss);
  }
}

// BN1 stats, stage 2: analytic mean/var -> scale/shift
__global__ void fin1_kernel(const float* __restrict__ sA1, const float* __restrict__ sAA1,
                            const float* __restrict__ sAc1, const float* __restrict__ scp,
                            const float* __restrict__ ssA, const float* __restrict__ sssA,
                            const float* __restrict__ gamma, const float* __restrict__ beta,
                            float* __restrict__ scale, float* __restrict__ shift) {
  int h = threadIdx.x;
  float sA = sA1[h], sAA = sAA1[h], sAc = sAc1[h];
  float sc = scp[0], scc = scp[1];
  float ss = ssA[h], sss = sssA[h];
  const float cnt = (float)MROWS;
  float mean = ((float)BB * sA + sc*ss) / cnt;
  float msq  = ((float)BB * sAA + 2.f*sAc*ss + scc*sss) / cnt;
  float var  = msq - mean*mean;
  float scl  = gamma[h] * rsqrtf(var + 1e-5f);
  scale[h] = scl; shift[h] = beta[h] - mean*scl;
}

// layer-1 output -> padded bf16 Xb [MT,256]; 4 ch/thread, loop-free
__global__ __launch_bounds__(256) void x2_kernel(
    const float* __restrict__ Abuf, const float* __restrict__ cbuf,
    const float* __restrict__ hcat, const float* __restrict__ scale,
    const float* __restrict__ shift, unsigned short* __restrict__ Xb) {
  int idx = blockIdx.x*256 + threadIdx.x;   // over MT*64
  int row = idx >> 6, h0 = (idx & 63)*4;
  int b = row >> 9, n = row & (NPAD-1);
  union { unsigned short u[4]; uint2 d; } p;
  p.d = make_uint2(0,0);
  if (n < NNODES) {
    float4 a  = *(const float4*)(Abuf + n*HH + h0);
    float4 s  = *(const float4*)(hcat + (size_t)(NKG + b)*HH + h0);
    float4 sc = *(const float4*)(scale + h0);
    float4 sh = *(const float4*)(shift + h0);
    float cn = cbuf[n];
    p.u[0] = f2bf(elu((a.x + cn*s.x)*sc.x + sh.x));
    p.u[1] = f2bf(elu((a.y + cn*s.y)*sc.y + sh.y));
    p.u[2] = f2bf(elu((a.z + cn*s.z)*sc.z + sh.z));
    p.u[3] = f2bf(elu((a.w + cn*s.w)*sc.w + sh.w));
  }
  *(uint2*)(Xb + (size_t)row*HH + h0) = p.d;
}

// ---------------- MFMA GEMM-T v3: 3-buffer, 2-deep prefetch; H[m][n] row-major out ----------
// H[m][n] = sum_k A[m,k]*Wt[n,k]; 128x256 tile, BK=32, 8 K-steps, vmcnt(12) steady state.
// FBN=1: BN2 finalize inline; A reg-staged (load at t for step t+1, transform AFTER MFMA so
// the load latency hides under the MFMA cluster), ds_write into buf (t+1)%3, lgkmcnt(0).
template<int FBN>
__global__ __launch_bounds__(256) void gemmT3_kernel(
    const unsigned short* __restrict__ Ag,   // Xb [MT,256] (raw layer-2 if FBN)
    const unsigned short* __restrict__ Bg,   // Wt [256,256] (n-major)
    const float* __restrict__ sums, const float* __restrict__ ssqs,
    const float* __restrict__ gamma, const float* __restrict__ beta,
    unsigned short* __restrict__ Hout) {     // [MT, 256] row-major h
  __shared__ __align__(16) unsigned short smem[36864];  // 72KB: As 3x4096, Bs 3x8192
  __shared__ float sclL[256], shfL[256];
  unsigned short* As = smem;            // 3 bufs x [128][32]
  unsigned short* Bs = smem + 12288;    // 3 bufs x [256][32]
  int tid = threadIdx.x;
  int wave = tid >> 6, lane = tid & 63;
  int l15 = lane & 15, quad = lane >> 4;
  int wm = (wave & 1) * 64;
  int wnh = wave >> 1;                  // n-half (0:[0,128), 1:[128,256))
  int row0 = blockIdx.x * 128;
  if (FBN) {
    float mean = sums[tid] * (1.f/(float)MROWS);
    float var  = ssqs[tid] * (1.f/(float)MROWS) - mean*mean;
    float s = gamma[tid] * rsqrtf(var + 1e-5f);
    sclL[tid] = s; shfL[tid] = beta[tid] - mean*s;
    __syncthreads();
  }
  // A chunks: 2/thread; B chunks: 4/thread (per BK=32 step)
  int c0 = tid, c1 = 256 + tid;
  int r0 = c0 >> 2, o0 = (c0 & 3) * 8;
  int r1 = c1 >> 2, o1 = (c1 & 3) * 8;
  const unsigned short* A0 = Ag + (size_t)(row0 + r0)*HH + o0;
  const unsigned short* A1 = Ag + (size_t)(row0 + r1)*HH + o1;

  auto XF = [&](uint4 v, int kk) -> uint4 {
    union { unsigned short u[8]; uint4 d; } va, pa;
    va.d = v;
#pragma unroll
    for (int s = 0; s < 8; ++s)
      pa.u[s] = f2bf(elu(bf2f(va.u[s])*sclL[kk+s] + shfL[kk+s]));
    return pa.d;
  };
  auto STAGE_B = [&](int kn, int buf) {
#pragma unroll
    for (int q = 0; q < 4; ++q) {
      int c = q*256 + tid;
      int rr = c >> 2, j = (c & 3)*8;
      stage16(Bg + (size_t)rr*HH + kn + j, Bs + buf*8192 + c*8);
    }
  };

  f32x4 acc[4][8] = {};
  // ---- prologue: steps 0 and 1 into bufs 0,1 ----
  if (FBN) {
    uint4 p00 = *(const uint4*)(A0);
    uint4 p01 = *(const uint4*)(A1);
    uint4 p10 = *(const uint4*)(A0 + 32);
    uint4 p11 = *(const uint4*)(A1 + 32);
    STAGE_B(0, 0);
    STAGE_B(32, 1);
    *(uint4*)(As + c0*8)        = XF(p00, o0);
    *(uint4*)(As + c1*8)        = XF(p01, o1);
    *(uint4*)(As + 4096 + c0*8) = XF(p10, 32 + o0);
    *(uint4*)(As + 4096 + c1*8) = XF(p11, 32 + o1);
    asm volatile("s_waitcnt lgkmcnt(0)" ::: "memory");
  } else {
    stage16(A0, As + c0*8);
    stage16(A1, As + c1*8);
    STAGE_B(0, 0);
    stage16(A0 + 32, As + 4096 + c0*8);
    stage16(A1 + 32, As + 4096 + c1*8);
    STAGE_B(32, 1);
  }
  uint4 na0, na1;
#pragma unroll
  for (int t = 0; t < 8; ++t) {
    int cur = t % 3;
    int nxt2 = (t + 2) % 3;
    if (FBN) {
      if (t >= 1 && t <= 6) {         // A(t+1) -> regs (A(0),A(1) done in prologue)
        na0 = *(const uint4*)(A0 + (t+1)*32);
        na1 = *(const uint4*)(A1 + (t+1)*32);
      }
      if (t < 6) STAGE_B((t+2)*32, nxt2);
      // ledger: t=0 outstanding B(1),B(2)=8 newer than B(0); t in[1,5]: B(t+1)4+na2+B(t+2)4=10;
      // t=6: B(7)4+na2=6; t=7: need B(7) -> 0
      if (t == 0)      asm volatile("s_waitcnt vmcnt(8)"  ::: "memory");
      else if (t <= 5) asm volatile("s_waitcnt vmcnt(10)" ::: "memory");
      else if (t == 6) asm volatile("s_waitcnt vmcnt(6)"  ::: "memory");
      else             asm volatile("s_waitcnt vmcnt(0)"  ::: "memory");
    } else {
      if (t < 6) {
        stage16(A0 + (t+2)*32, As + nxt2*4096 + c0*8);
        stage16(A1 + (t+2)*32, As + nxt2*4096 + c1*8);
        STAGE_B((t+2)*32, nxt2);
        asm volatile("s_waitcnt vmcnt(12)" ::: "memory");   // retires step t's 6
      } else if (t == 6) {
        asm volatile("s_waitcnt vmcnt(6)" ::: "memory");
      } else {
        asm volatile("s_waitcnt vmcnt(0)" ::: "memory");
      }
    }
    __builtin_amdgcn_s_barrier();
    __builtin_amdgcn_sched_barrier(0);
    short8 af[4], bfv[8];
#pragma unroll
    for (int i = 0; i < 4; ++i)
      af[i] = *(const short8*)(As + cur*4096 + (wm + i*16 + l15)*32 + quad*8);
#pragma unroll
    for (int i = 0; i < 8; ++i)
      bfv[i] = *(const short8*)(Bs + cur*8192 + (wnh*128 + i*16 + l15)*32 + quad*8);
#pragma unroll
    for (int mi = 0; mi < 4; ++mi)
#pragma unroll
      for (int ni = 0; ni < 8; ++ni)
        mfma16(acc[mi][ni], af[mi], bfv[ni]);
    if (FBN && t >= 1 && t <= 6) {
      // transform A(t+1) regs (loaded this step; latency hidden under MFMA) -> buf (t+1)%3
      int nb = (t + 1) % 3;
      int kk = (t + 1) * 32;
      *(uint4*)(As + nb*4096 + c0*8) = XF(na0, kk + o0);
      *(uint4*)(As + nb*4096 + c1*8) = XF(na1, kk + o1);
      asm volatile("s_waitcnt lgkmcnt(0)" ::: "memory");
    }
    __builtin_amdgcn_sched_barrier(0);
    __builtin_amdgcn_s_barrier();
  }
  asm volatile("s_nop 7\n\ts_nop 7" ::);
  // epilogue: acc -> smem[m][n] (full 128x256, EP2 pad), then coalesced row-major writes
#pragma unroll
  for (int ni = 0; ni < 8; ++ni) {
    int nl = wnh*128 + ni*16 + l15;
#pragma unroll
    for (int mi = 0; mi < 4; ++mi) {
      int ml = wm + mi*16 + quad*4;
#pragma unroll
      for (int r = 0; r < 4; ++r)
        smem[(ml + r)*EP2 + nl] = f2bf(acc[mi][ni][r]);
    }
  }
  __syncthreads();
  int colq = (tid & 31) * 8;
  int rbase = tid >> 5;
#pragma unroll
  for (int j = 0; j < 16; ++j) {
    int row = j*8 + rbase;
    uint4 d = *(const uint4*)(smem + row*EP2 + colq);
    *(uint4*)(Hout + (size_t)(row0 + row)*HH + colq) = d;
  }
}

// ---------------- sparse CSR aggregation v4: LDS H-slice + LDS colA + 2-edge unroll --------
// Round-12 diagnosis: per-edge chain had a GLOBAL colA load (L2 ~200cy) feeding the ds_read
// address at 1 wave/SIMD occupancy -> fully serialized (~630cy/edge, 73.6us). Fix: colA
// lives in LDS (18KB; total 149.6KB static LDS) and the 2-edge unroll issues both edges'
// ds_reads together, so the chain is ds(colL)+ds(Hs) ~250cy per PAIR. valA stays global
// (chain-independent, L2-hot broadcast).
__global__ __launch_bounds__(256) void agg4_kernel(
    const int* __restrict__ rp, const int* __restrict__ colA,
    const float* __restrict__ valA, const unsigned short* __restrict__ H,
    unsigned short* __restrict__ Xbo,
    float* __restrict__ sums, float* __restrict__ ssqs) {
  __shared__ __align__(16) unsigned short Hs[NNODES*128];  // 128512 B
  __shared__ int colL[NET];                                // 18008 B
  __shared__ int rpL[NNODES+1];                            // 2012 B
  __shared__ float red[256];                               // 1024 B  (~149.6 KB total)
  int id = blockIdx.x;
  int b = id >> 1, half = id & 1;
  int tid = threadIdx.x;
  // stage H[b*512+row][half*128 ..) -> Hs[row*128], linear LDS (8032 x 16B chunks)
  const unsigned short* Hbase = H + (size_t)b*NPAD*HH + half*128;
  for (int c = tid; c < NNODES*16; c += 256) {
    int row = c >> 4, seg = c & 15;
    stage16(Hbase + (size_t)row*HH + seg*8, Hs + c*8);
  }
  for (int i = tid; i < NET; i += 256) colL[i] = colA[i];
  for (int i = tid; i < NNODES+1; i += 256) rpL[i] = rp[i];
  red[tid] = 0.f;
  __syncthreads();   // drains vmcnt + lgkm; Hs/colL/rpL ready
  int chg = tid & 15;          // channel octet within the half
  int dstg = tid >> 4;         // dst stride group (16)
  int cbase = chg * 8;
  float psum[8] = {0,0,0,0,0,0,0,0}, psq[8] = {0,0,0,0,0,0,0,0};
  for (int dst = dstg; dst < NNODES; dst += 16) {
    int s = rpL[dst], e = rpL[dst+1];
    float acc[8] = {0,0,0,0,0,0,0,0};
    int t = s;
    for (; t + 1 < e; t += 2) {
      int cl0 = colL[t], cl1 = colL[t+1];       // LDS
      float v0 = valA[t], v1 = valA[t+1];       // global (L2), chain-independent
      union { unsigned short u[8]; uint4 d; } w0, w1;
      w0.d = *(const uint4*)(Hs + cl0*128 + cbase);   // ds_read_b128 x2, issued together
      w1.d = *(const uint4*)(Hs + cl1*128 + cbase);
#pragma unroll
      for (int j = 0; j < 8; ++j)
        acc[j] += v0 * bf2f(w0.u[j]) + v1 * bf2f(w1.u[j]);
    }
    if (t < e) {
      int cl0 = colL[t]; float v0 = valA[t];
      union { unsigned short u[8]; uint4 d; } w;
      w.d = *(const uint4*)(Hs + cl0*128 + cbase);
#pragma unroll
      for (int j = 0; j < 8; ++j)
        acc[j] += v0 * bf2f(w.u[j]);
    }
    union { unsigned short u[8]; uint4 d; } p;
#pragma unroll
    for (int j = 0; j < 8; ++j) {
      float v = acc[j];
      p.u[j] = f2bf(v);
      psum[j] += v; psq[j] += v*v;
    }
    *(uint4*)(Xbo + (size_t)b*NPAD*HH + (size_t)dst*HH + half*128 + cbase) = p.d;
  }
#pragma unroll
  for (int j = 0; j < 8; ++j) {
    atomicAdd(&red[cbase + j], psum[j]);
    atomicAdd(&red[128 + cbase + j], psq[j]);
  }
  __syncthreads();
  if (tid < 128) atomicAdd(&sums[half*128 + tid], red[tid]);
  else           atomicAdd(&ssqs[half*128 + tid - 128], red[tid]);
}

__global__ void finalize_kernel(const float* __restrict__ sums, const float* __restrict__ ssqs,
                                const float* __restrict__ gamma, const float* __restrict__ beta,
                                float* __restrict__ scale, float* __restrict__ shift) {
  int h = threadIdx.x;
  const float cnt = (float)MROWS;
  float mean = sums[h] / cnt;
  float var  = ssqs[h] / cnt - mean*mean;
  float scl  = gamma[h] * rsqrtf(var + 1e-5f);
  scale[h] = scl; shift[h] = beta[h] - mean*scl;
}

// final BN+ELU: read bf16 Xb (raw layer-3 pre-BN), write fp32 d_out
__global__ __launch_bounds__(256) void bnout_kernel(
    const unsigned short* __restrict__ Xb, const float* __restrict__ scale,
    const float* __restrict__ shift, float* __restrict__ O) {
  int idx = blockIdx.x*256 + threadIdx.x;   // over MT*64
  int row = idx >> 6, h0 = (idx & 63)*4;
  int b = row >> 9, n = row & (NPAD-1);
  if (n >= NNODES) return;
  union { unsigned short u[4]; uint2 d; } v;
  v.d = *(const uint2*)(Xb + (size_t)row*HH + h0);
  float4 sc = *(const float4*)(scale + h0);
  float4 sh = *(const float4*)(shift + h0);
  float4 o;
  o.x = elu(bf2f(v.u[0])*sc.x + sh.x);
  o.y = elu(bf2f(v.u[1])*sc.y + sh.y);
  o.z = elu(bf2f(v.u[2])*sc.z + sh.z);
  o.w = elu(bf2f(v.u[3])*sc.w + sh.w);
  *(float4*)(O + ((size_t)(b*NNODES + n)*HH + h0)) = o;
}

extern "C" void kernel_launch(void* const* d_in, const int* in_sizes, int n_in,
                              void* d_out, int out_size, void* d_ws, size_t ws_size,
                              hipStream_t stream) {
  const float* sensor = (const float*)d_in[0];
  const float* base   = (const float*)d_in[1];
  const int*   eidx   = (const int*)d_in[2];
  const float* W1 = (const float*)d_in[3];
  const float* g1 = (const float*)d_in[5];
  const float* be1= (const float*)d_in[6];
  const float* W2 = (const float*)d_in[7];
  const float* g2 = (const float*)d_in[9];
  const float* be2= (const float*)d_in[10];
  const float* W3 = (const float*)d_in[11];
  const float* g3 = (const float*)d_in[13];
  const float* be3= (const float*)d_in[14];

  char* ws = (char*)d_ws;
  // ---- zeroed region [0, 16384) ----
  int*   deg    = (int*)(ws + 0);
  float* sum2   = (float*)(ws + 2048);
  float* ssq2   = (float*)(ws + 3072);
  float* sum3   = (float*)(ws + 4096);
  float* ssq3   = (float*)(ws + 5120);
  float* cbuf   = (float*)(ws + 6144);
  int*   cursor = (int*)(ws + 8192);
  float* sA1    = (float*)(ws + 10496);
  float* sAA1   = (float*)(ws + 11520);
  float* sAc1   = (float*)(ws + 12544);
  float* scp    = (float*)(ws + 13568);
  float* ssA    = (float*)(ws + 13824);
  float* sssA   = (float*)(ws + 14848);
  // ---- end zeroed ----
  float* dinv   = (float*)(ws + 16384);
  int*   rp     = (int*)(ws + 18432);
  int*   colA   = (int*)(ws + 20480);
  float* valA   = (float*)(ws + 40960);
  float* scale1 = (float*)(ws + 61440);
  float* shift1 = (float*)(ws + 62464);
  float* scale3 = (float*)(ws + 65536);
  float* shift3 = (float*)(ws + 66560);
  float* Abuf   = (float*)(ws + 67584);                  // 502*256 f32
  float* hcat   = (float*)(ws + 581632);                 // 628*256 f32
  unsigned short* Wt2 = (unsigned short*)(ws + 1224704); // 256*256 bf16
  unsigned short* Wt3 = (unsigned short*)(ws + 1355776);
  unsigned short* Xb  = (unsigned short*)(ws + 2011136); // MT*256 bf16
  unsigned short* Hbuf= (unsigned short*)(ws + 35565568UL); // MT*256 bf16 (h = X*W)
  // Xp1/Wt1 alias the Hbuf region: only used before first gemmT3 writes H
  unsigned short* Xp1 = (unsigned short*)(ws + 35565568UL);            // 640*1024
  unsigned short* Wt1 = (unsigned short*)(ws + 35565568UL + 1310720);  // 256*1024
  float* out = (float*)d_out;

  hipMemsetAsync(ws, 0, 16384, stream);
  deg_kernel<<<(NET+255)/256, 256, 0, stream>>>(eidx, deg);
  scan_kernel<<<1, 512, 0, stream>>>(deg, dinv, rp, cursor);
  fill_kernel<<<(NET+255)/256, 256, 0, stream>>>(eidx, dinv, cursor, colA, valA);
  prep_kernel<<<2036, 256, 0, stream>>>(W1, W2, W3, base, sensor, Wt1, Wt2, Wt3, Xp1, hcat);

  gemm1m_kernel<<<dim3(2, 5, 4), 256, 0, stream>>>(Xp1, Wt1, hcat);
  ac_kernel<<<NNODES, 256, 0, stream>>>(rp, colA, valA, hcat, Abuf, cbuf);
  bn1n_kernel<<<40, 256, 0, stream>>>(Abuf, cbuf, hcat, sA1, sAA1, sAc1, scp, ssA, sssA);
  fin1_kernel<<<1, 256, 0, stream>>>(sA1, sAA1, sAc1, scp, ssA, sssA, g1, be1, scale1, shift1);
  x2_kernel<<<(MT*64)/256, 256, 0, stream>>>(Abuf, cbuf, hcat, scale1, shift1, Xb);

  // layer 2: dense h = Xb*W2, then sparse aggregation (LDS-gather, LDS indices)
  gemmT3_kernel<0><<<MT/128, 256, 0, stream>>>(Xb, Wt2, sum2, ssq2, g2, be2, Hbuf);
  agg4_kernel<<<256, 256, 0, stream>>>(rp, colA, valA, Hbuf, Xb, sum2, ssq2);
  // layer 3: BN2 finalize+apply fused into pipelined A-staging of gemmT3<1>
  gemmT3_kernel<1><<<MT/128, 256, 0, stream>>>(Xb, Wt3, sum2, ssq2, g2, be2, Hbuf);
  agg4_kernel<<<256, 256, 0, stream>>>(rp, colA, valA, Hbuf, Xb, sum3, ssq3);
  finalize_kernel<<<1, 256, 0, stream>>>(sum3, ssq3, g3, be3, scale3, shift3);
  bnout_kernel<<<(MT*64)/256, 256, 0, stream>>>(Xb, scale3, shift3, out);
}

// Round 14
// 288.615 us; speedup vs baseline: 2.3756x; 1.0956x over previous
//
#include <hip/hip_runtime.h>
#include <cstdint>
#include <cstddef>

#define NNODES 502
#define NKG    500
#define NPAD   512
#define NEDGE  4000
#define NET    4502   // NEDGE + NNODES self loops
#define BB     128
#define DD     1024
#define HH     256
#define MROWS  (BB*NNODES)   // 64256
#define MT     65536         // BB*NPAD padded rows
#define MCAT   628           // NKG + BB rows in hcat
#define EPITCH 136           // padded bf16 row stride for epilogue transpose

typedef short short8 __attribute__((ext_vector_type(8)));
typedef float f32x4  __attribute__((ext_vector_type(4)));

__device__ __forceinline__ unsigned short f2bf(float f) {
  union { float f; unsigned int u; } v; v.f = f;
  unsigned int r = v.u + 0x7fffu + ((v.u >> 16) & 1u);
  return (unsigned short)(r >> 16);
}

__device__ __forceinline__ float bf2f(unsigned short u) {
  union { unsigned int u; float f; } v; v.u = ((unsigned int)u) << 16;
  return v.f;
}

__device__ __forceinline__ float elu(float y) {
  return (y > 0.f) ? y : (__expf(y) - 1.f);
}

// async global->LDS, 16B per lane; LDS dest = wave-uniform base + lane*16
__device__ __forceinline__ void stage16(const void* g, void* l) {
  __builtin_amdgcn_global_load_lds((__attribute__((address_space(1))) void*)g,
                                   (__attribute__((address_space(3))) void*)l, 16, 0, 0);
}

__device__ __forceinline__ void mfma16(f32x4& c, short8 a, short8 b) {
  asm volatile("v_mfma_f32_16x16x32_bf16 %0, %1, %2, %0" : "+v"(c) : "v"(a), "v"(b));
}

// ---------------- edge helpers ----------------
__device__ inline void get_edge(const int* __restrict__ e, int i, int i64mode,
                                int& src, int& dst) {
  if (i < NEDGE) {
    if (i64mode) { src = e[2*i]; dst = e[2*NEDGE + 2*i]; }
    else         { src = e[i];   dst = e[NEDGE + i]; }
  } else {
    src = dst = i - NEDGE;   // self loop
  }
  src = min(max(src, 0), NNODES-1);
  dst = min(max(dst, 0), NNODES-1);
}

// per-block int64-layout detection (uniform barriers; all threads reach)
__device__ __forceinline__ int detect_mode(const int* __restrict__ e) {
  __shared__ int sflag;
  if (threadIdx.x == 0) sflag = 0;
  __syncthreads();
  if (e[2*threadIdx.x + 1] != 0) atomicOr(&sflag, 1);
  __syncthreads();
  return sflag == 0;   // 1 => int64 layout
}

__global__ void deg_kernel(const int* __restrict__ e, int* __restrict__ deg) {
  int i64 = detect_mode(e);
  int i = blockIdx.x*256 + threadIdx.x;
  if (i >= NET) return;
  int src, dst; get_edge(e, i, i64, src, dst);
  atomicAdd(&deg[dst], 1);
}

__global__ void scan_kernel(const int* __restrict__ deg, float* __restrict__ dinv,
                            int* __restrict__ rp, int* __restrict__ cursor) {
  __shared__ int s[512];
  int t = threadIdx.x;
  int cnt = (t < NNODES) ? deg[t] : 0;
  s[t] = cnt;
  if (t < NNODES) dinv[t] = rsqrtf((float)cnt);
  __syncthreads();
  for (int off = 1; off < 512; off <<= 1) {
    int v = (t >= off) ? s[t-off] : 0;
    __syncthreads();
    s[t] += v;
    __syncthreads();
  }
  if (t == 0) rp[0] = 0;
  if (t < NNODES) { rp[t+1] = s[t]; cursor[t] = s[t] - cnt; }
}

// fused CSR fill + dense normalized adjacency accumulate (fp32 scratch in d_out)
__global__ void fillsdf_kernel(const int* __restrict__ e, const float* __restrict__ dinv,
                               int* __restrict__ cursor, int* __restrict__ colA,
                               float* __restrict__ valA, float* __restrict__ Sdf) {
  int i64 = detect_mode(e);
  int i = blockIdx.x*256 + threadIdx.x;
  if (i >= NET) return;
  int src, dst; get_edge(e, i, i64, src, dst);
  float v = dinv[src] * dinv[dst];
  int pos = atomicAdd(&cursor[dst], 1);
  colA[pos] = src;
  valA[pos] = v;
  atomicAdd(&Sdf[dst*NPAD + src], v);
}

__global__ void sdcvt_kernel(const float* __restrict__ Sdf, unsigned short* __restrict__ Sd) {
  int i = blockIdx.x*256 + threadIdx.x;   // 512*512
  Sd[i] = f2bf(Sdf[i]);
}

// fused prep: Wt2/Wt3 (blocks 0..511), Wt1 (512..767), Xp1 (768..1407), hcat zero (1408..2035)
__global__ __launch_bounds__(256) void prep_kernel(
    const float* __restrict__ W1, const float* __restrict__ W2, const float* __restrict__ W3,
    const float* __restrict__ base, const float* __restrict__ sensor,
    unsigned short* __restrict__ Wt1, unsigned short* __restrict__ Wt2,
    unsigned short* __restrict__ Wt3, unsigned short* __restrict__ Xp1,
    float* __restrict__ hcatz) {
  int bid = blockIdx.x, tid = threadIdx.x;
  if (bid < 512) {
    const float* W = (bid & 256) ? W3 : W2;
    unsigned short* Wt = (bid & 256) ? Wt3 : Wt2;
    int n = bid & 255;
    Wt[n*HH + tid] = f2bf(W[(size_t)tid*HH + n]);
  } else if (bid < 768) {
    int n = bid - 512;
    for (int k = tid; k < DD; k += 256)
      Wt1[n*DD + k] = f2bf(W1[(size_t)k*HH + n]);
  } else if (bid < 1408) {
    int i = (bid - 768)*256 + tid;   // over 640*256, 4 elems each
    int r = i >> 8, c = (i & 255) * 4;
    float4 v = make_float4(0.f, 0.f, 0.f, 0.f);
    if (r < NKG) v = *(const float4*)&base[(size_t)r*DD + c];
    else if (r < MCAT) v = *(const float4*)&sensor[(size_t)(r-NKG)*DD + c];
    union { unsigned short u[4]; uint2 d; } p;
    p.u[0]=f2bf(v.x); p.u[1]=f2bf(v.y); p.u[2]=f2bf(v.z); p.u[3]=f2bf(v.w);
    *(uint2*)&Xp1[(size_t)r*DD + c] = p.d;
  } else {
    hcatz[(bid - 1408)*256 + tid] = 0.f;   // 628 rows
  }
}

// ---------------- layer-1 MFMA GEMM, split-K x4: hcat += Xp1*Wt1^T ----------------
__global__ __launch_bounds__(256) void gemm1m_kernel(
    const unsigned short* __restrict__ Ag,   // [640,1024]
    const unsigned short* __restrict__ Bg,   // [256,1024]
    float* __restrict__ C) {                 // [628,256] fp32 (pre-zeroed)
  __shared__ unsigned short As[128*32];
  __shared__ unsigned short Bs[128*32];
  int tid = threadIdx.x;
  int wave = tid >> 6, lane = tid & 63;
  int l15 = lane & 15, quad = lane >> 4;
  int wm = (wave & 1) * 64, wn = (wave >> 1) * 64;
  int row0 = blockIdx.y * 128, col0 = blockIdx.x * 128;
  int kbase = blockIdx.z * 256;
  f32x4 acc[4][4] = {};
  for (int k0 = kbase; k0 < kbase + 256; k0 += 32) {
#pragma unroll
    for (int q = 0; q < 2; ++q) {
      int c = wave*128 + q*64 + lane;
      stage16(Ag + (size_t)(row0 + (c>>2))*DD + k0 + (c&3)*8, As + c*8);
      stage16(Bg + (size_t)(col0 + (c>>2))*DD + k0 + (c&3)*8, Bs + c*8);
    }
    __syncthreads();
    short8 af[4], bfv[4];
#pragma unroll
    for (int i = 0; i < 4; ++i) {
      af[i]  = *(const short8*)(As + (wm + i*16 + l15)*32 + quad*8);
      bfv[i] = *(const short8*)(Bs + (wn + i*16 + l15)*32 + quad*8);
    }
#pragma unroll
    for (int mi = 0; mi < 4; ++mi)
#pragma unroll
      for (int ni = 0; ni < 4; ++ni)
        mfma16(acc[mi][ni], af[mi], bfv[ni]);
    __syncthreads();
  }
  asm volatile("s_nop 7\n\ts_nop 7" ::);
#pragma unroll
  for (int ni = 0; ni < 4; ++ni) {
    int n = col0 + wn + ni*16 + l15;
#pragma unroll
    for (int mi = 0; mi < 4; ++mi) {
      int m = row0 + wm + mi*16 + quad*4;
#pragma unroll
      for (int r = 0; r < 4; ++r)
        if (m + r < MCAT) atomicAdd(&C[(size_t)(m+r)*HH + n], acc[mi][ni][r]);
    }
  }
}

// layer-1 decomposition: A[n,h] over shared srcs, c[n] = coeff of sensor row
__global__ void ac_kernel(const int* __restrict__ rp, const int* __restrict__ colA,
                          const float* __restrict__ valA, const float* __restrict__ hcat,
                          float* __restrict__ Abuf, float* __restrict__ cbuf) {
  int n = blockIdx.x, h = threadIdx.x;
  int s = rp[n], e = rp[n+1];
  float acc = 0.f, cacc = 0.f;
  for (int t = s; t < e; ++t) {
    int cl = colA[t]; float v = valA[t];
    if (cl < NKG) acc += v * hcat[cl*HH + h];
    else if (cl == NKG) cacc += v;
  }
  Abuf[n*HH + h] = acc;
  if (h == 0) cbuf[n] = cacc;
}

// BN1 stats, stage 1: parallel partial sums. blocks 0..31: nodes; 32..39: sensor rows.
__global__ __launch_bounds__(256) void bn1n_kernel(
    const float* __restrict__ Abuf, const float* __restrict__ cbuf,
    const float* __restrict__ hcat,
    float* __restrict__ sA1, float* __restrict__ sAA1, float* __restrict__ sAc1,
    float* __restrict__ scp, float* __restrict__ ssA, float* __restrict__ sssA) {
  int bid = blockIdx.x, h = threadIdx.x;
  if (bid < 32) {
    int n0 = bid*16, n1 = min(n0+16, NNODES);
    float sA = 0, sAA = 0, sAc = 0, sc = 0, scc = 0;
    for (int n = n0; n < n1; ++n) {
      float a = Abuf[n*HH + h]; float cn = cbuf[n];
      sA += a; sAA += a*a; sAc += a*cn; sc += cn; scc += cn*cn;
    }
    atomicAdd(&sA1[h], sA); atomicAdd(&sAA1[h], sAA); atomicAdd(&sAc1[h], sAc);
    if (h == 0) { atomicAdd(&scp[0], sc); atomicAdd(&scp[1], scc); }
  } else {
    int b0 = (bid-32)*16;
    float ss = 0, sss = 0;
    for (int b = b0; b < b0+16; ++b) {
      float v = hcat[(size_t)(NKG + b)*HH + h]; ss += v; sss += v*v;
    }
    atomicAdd(&ssA[h], ss); atomicAdd(&sssA[h], sss);
  }
}

// BN1 stats, stage 2: analytic mean/var -> scale/shift
__global__ void fin1_kernel(const float* __restrict__ sA1, const float* __restrict__ sAA1,
                            const float* __restrict__ sAc1, const float* __restrict__ scp,
                            const float* __restrict__ ssA, const float* __restrict__ sssA,
                            const float* __restrict__ gamma, const float* __restrict__ beta,
                            float* __restrict__ scale, float* __restrict__ shift) {
  int h = threadIdx.x;
  float sA = sA1[h], sAA = sAA1[h], sAc = sAc1[h];
  float sc = scp[0], scc = scp[1];
  float ss = ssA[h], sss = sssA[h];
  const float cnt = (float)MROWS;
  float mean = ((float)BB * sA + sc*ss) / cnt;
  float msq  = ((float)BB * sAA + 2.f*sAc*ss + scc*sss) / cnt;
  float var  = msq - mean*mean;
  float scl  = gamma[h] * rsqrtf(var + 1e-5f);
  scale[h] = scl; shift[h] = beta[h] - mean*scl;
}

// layer-1 output -> padded bf16 Xb [MT,256]; 4 ch/thread, loop-free
__global__ __launch_bounds__(256) void x2_kernel(
    const float* __restrict__ Abuf, const float* __restrict__ cbuf,
    const float* __restrict__ hcat, const float* __restrict__ scale,
    const float* __restrict__ shift, unsigned short* __restrict__ Xb) {
  int idx = blockIdx.x*256 + threadIdx.x;   // over MT*64
  int row = idx >> 6, h0 = (idx & 63)*4;
  int b = row >> 9, n = row & (NPAD-1);
  union { unsigned short u[4]; uint2 d; } p;
  p.d = make_uint2(0,0);
  if (n < NNODES) {
    float4 a  = *(const float4*)(Abuf + n*HH + h0);
    float4 s  = *(const float4*)(hcat + (size_t)(NKG + b)*HH + h0);
    float4 sc = *(const float4*)(scale + h0);
    float4 sh = *(const float4*)(shift + h0);
    float cn = cbuf[n];
    p.u[0] = f2bf(elu((a.x + cn*s.x)*sc.x + sh.x));
    p.u[1] = f2bf(elu((a.y + cn*s.y)*sc.y + sh.y));
    p.u[2] = f2bf(elu((a.z + cn*s.z)*sc.z + sh.z));
    p.u[3] = f2bf(elu((a.w + cn*s.w)*sc.w + sh.w));
  }
  *(uint2*)(Xb + (size_t)row*HH + h0) = p.d;
}

// ---------------- MFMA GEMM-T v3: 3-buffer, 2-deep prefetch (gemmS2 schedule) ----------------
// Tt[n][m] = sum_k A[m,k]*Wt[n,k]; 128x256 tile, BK=32, 8 K-steps, vmcnt(12) steady state.
// FBN=1: BN2 finalize inline; A reg-staged (load at t for step t+1, transform AFTER MFMA so
// the load latency hides under the MFMA cluster), ds_write into buf (t+1)%3, lgkmcnt(0).
template<int FBN>
__global__ __launch_bounds__(256) void gemmT3_kernel(
    const unsigned short* __restrict__ Ag,   // Xb [MT,256] (raw layer-2 if FBN)
    const unsigned short* __restrict__ Bg,   // Wt [256,256] (n-major)
    const float* __restrict__ sums, const float* __restrict__ ssqs,
    const float* __restrict__ gamma, const float* __restrict__ beta,
    unsigned short* __restrict__ Tt) {       // [256, MT]
  __shared__ __align__(16) unsigned short smem[36864];  // 72KB: As 3x4096, Bs 3x8192
  __shared__ float sclL[256], shfL[256];
  unsigned short* As = smem;            // 3 bufs x [128][32]
  unsigned short* Bs = smem + 12288;    // 3 bufs x [256][32]
  int tid = threadIdx.x;
  int wave = tid >> 6, lane = tid & 63;
  int l15 = lane & 15, quad = lane >> 4;
  int wm = (wave & 1) * 64;
  int wnh = wave >> 1;                  // n-half (0:[0,128), 1:[128,256))
  int row0 = blockIdx.x * 128;
  if (FBN) {
    float mean = sums[tid] * (1.f/(float)MROWS);
    float var  = ssqs[tid] * (1.f/(float)MROWS) - mean*mean;
    float s = gamma[tid] * rsqrtf(var + 1e-5f);
    sclL[tid] = s; shfL[tid] = beta[tid] - mean*s;
    __syncthreads();
  }
  // A chunks: 2/thread; B chunks: 4/thread (per BK=32 step)
  int c0 = tid, c1 = 256 + tid;
  int r0 = c0 >> 2, o0 = (c0 & 3) * 8;
  int r1 = c1 >> 2, o1 = (c1 & 3) * 8;
  const unsigned short* A0 = Ag + (size_t)(row0 + r0)*HH + o0;
  const unsigned short* A1 = Ag + (size_t)(row0 + r1)*HH + o1;

  auto XF = [&](uint4 v, int kk) -> uint4 {
    union { unsigned short u[8]; uint4 d; } va, pa;
    va.d = v;
#pragma unroll
    for (int s = 0; s < 8; ++s)
      pa.u[s] = f2bf(elu(bf2f(va.u[s])*sclL[kk+s] + shfL[kk+s]));
    return pa.d;
  };
  auto STAGE_B = [&](int kn, int buf) {
#pragma unroll
    for (int q = 0; q < 4; ++q) {
      int c = q*256 + tid;
      int rr = c >> 2, j = (c & 3)*8;
      stage16(Bg + (size_t)rr*HH + kn + j, Bs + buf*8192 + c*8);
    }
  };

  f32x4 acc[4][8] = {};
  // ---- prologue: steps 0 and 1 into bufs 0,1 ----
  if (FBN) {
    uint4 p00 = *(const uint4*)(A0);
    uint4 p01 = *(const uint4*)(A1);
    uint4 p10 = *(const uint4*)(A0 + 32);
    uint4 p11 = *(const uint4*)(A1 + 32);
    STAGE_B(0, 0);
    STAGE_B(32, 1);
    *(uint4*)(As + c0*8)        = XF(p00, o0);
    *(uint4*)(As + c1*8)        = XF(p01, o1);
    *(uint4*)(As + 4096 + c0*8) = XF(p10, 32 + o0);
    *(uint4*)(As + 4096 + c1*8) = XF(p11, 32 + o1);
    asm volatile("s_waitcnt lgkmcnt(0)" ::: "memory");
  } else {
    stage16(A0, As + c0*8);
    stage16(A1, As + c1*8);
    STAGE_B(0, 0);
    stage16(A0 + 32, As + 4096 + c0*8);
    stage16(A1 + 32, As + 4096 + c1*8);
    STAGE_B(32, 1);
  }
  uint4 na0, na1;
#pragma unroll
  for (int t = 0; t < 8; ++t) {
    int cur = t % 3;
    int nxt2 = (t + 2) % 3;
    if (FBN) {
      if (t >= 1 && t <= 6) {         // A(t+1) -> regs (A(0),A(1) done in prologue)
        na0 = *(const uint4*)(A0 + (t+1)*32);
        na1 = *(const uint4*)(A1 + (t+1)*32);
      }
      if (t < 6) STAGE_B((t+2)*32, nxt2);
      // ledger: t=0 outstanding B(1),B(2)=8 newer than B(0); t in[1,5]: B(t+1)4+na2+B(t+2)4=10;
      // t=6: B(7)4+na2=6; t=7: need B(7) -> 0
      if (t == 0)      asm volatile("s_waitcnt vmcnt(8)"  ::: "memory");
      else if (t <= 5) asm volatile("s_waitcnt vmcnt(10)" ::: "memory");
      else if (t == 6) asm volatile("s_waitcnt vmcnt(6)"  ::: "memory");
      else             asm volatile("s_waitcnt vmcnt(0)"  ::: "memory");
    } else {
      if (t < 6) {
        stage16(A0 + (t+2)*32, As + nxt2*4096 + c0*8);
        stage16(A1 + (t+2)*32, As + nxt2*4096 + c1*8);
        STAGE_B((t+2)*32, nxt2);
        asm volatile("s_waitcnt vmcnt(12)" ::: "memory");   // retires step t's 6
      } else if (t == 6) {
        asm volatile("s_waitcnt vmcnt(6)" ::: "memory");
      } else {
        asm volatile("s_waitcnt vmcnt(0)" ::: "memory");
      }
    }
    __builtin_amdgcn_s_barrier();
    __builtin_amdgcn_sched_barrier(0);
    short8 af[4], bfv[8];
#pragma unroll
    for (int i = 0; i < 4; ++i)
      af[i] = *(const short8*)(As + cur*4096 + (wm + i*16 + l15)*32 + quad*8);
#pragma unroll
    for (int i = 0; i < 8; ++i)
      bfv[i] = *(const short8*)(Bs + cur*8192 + (wnh*128 + i*16 + l15)*32 + quad*8);
#pragma unroll
    for (int mi = 0; mi < 4; ++mi)
#pragma unroll
      for (int ni = 0; ni < 8; ++ni)
        mfma16(acc[mi][ni], af[mi], bfv[ni]);
    if (FBN && t >= 1 && t <= 6) {
      // transform A(t+1) regs (loaded this step; latency hidden under MFMA) -> buf (t+1)%3
      int nb = (t + 1) % 3;
      int kk = (t + 1) * 32;
      *(uint4*)(As + nb*4096 + c0*8) = XF(na0, kk + o0);
      *(uint4*)(As + nb*4096 + c1*8) = XF(na1, kk + o1);
      asm volatile("s_waitcnt lgkmcnt(0)" ::: "memory");
    }
    __builtin_amdgcn_sched_barrier(0);
    __builtin_amdgcn_s_barrier();
  }
  asm volatile("s_nop 7\n\ts_nop 7" ::);
  // transposed epilogue in two n-halves (scratch reuses smem), n-major coalesced writes
  int moff = (tid & 15)*8;
#pragma unroll
  for (int nh = 0; nh < 2; ++nh) {
    if (wnh == nh) {
#pragma unroll
      for (int ni = 0; ni < 8; ++ni) {
        int nl = ni*16 + l15;
#pragma unroll
        for (int mi = 0; mi < 4; ++mi) {
          int ml = wm + mi*16 + quad*4;
#pragma unroll
          for (int r = 0; r < 4; ++r)
            smem[nl*EPITCH + ml + r] = f2bf(acc[mi][ni][r]);
        }
      }
    }
    __syncthreads();
#pragma unroll
    for (int j = 0; j < 8; ++j) {
      int nr = (tid >> 4) + j*16;
      uint4 d = *(const uint4*)(smem + nr*EPITCH + moff);
      *(uint4*)(Tt + (size_t)(nh*128 + nr)*MT + row0 + moff) = d;
    }
    __syncthreads();
  }
}

// ---------------- MFMA GEMM-S v2: 2 batches/block, 3-buffer, 2-deep prefetch ----------------
// Xbo[(b+bb)*512+node][n] = bf16(sum_k Sd[node][k]*Tt[n][(b+bb)*512+k]); BN stats from fp32 acc.
__global__ __launch_bounds__(256) void gemmS2_kernel(
    const unsigned short* __restrict__ Sd,   // [512,512]
    const unsigned short* __restrict__ Tt,   // [256, MT]
    unsigned short* __restrict__ Xbo,        // [MT,256] bf16 (pads untouched)
    float* __restrict__ sums, float* __restrict__ ssqs) {
  __shared__ __align__(16) unsigned short smem[36864];  // 72KB: As 3x4096, Bs 3x8192
  unsigned short* As = smem;            // 3 bufs x [128][32]
  unsigned short* Bs = smem + 12288;    // 3 bufs x 2 batches x [128][32]
  int tid = threadIdx.x;
  int wave = tid >> 6, lane = tid & 63;
  int l15 = lane & 15, quad = lane >> 4;
  int wm = (wave & 1) * 64, wn = (wave >> 1) * 64;
  // 512 blocks = 4 y-tiles x 2 x-tiles x 64 batch-pairs; y-tiles of one strip share an XCD
  int id = blockIdx.x;
  int xcd = id & 7;
  int w = id >> 3;
  int y = w & 3;
  int g = (w >> 2) * 8 + xcd;    // 0..127
  int x = g >> 6;                // col tile (2)
  int b = (g & 63) * 2;          // batch pair base
  int row0 = y * 128, col0 = x * 128;
  const unsigned short* Abase = Sd + (size_t)row0*NPAD;
  const unsigned short* Bbase = Tt + (size_t)col0*MT + (size_t)b*NPAD;
  int c0 = tid, c1 = 256 + tid;
  int r0 = c0 >> 2, o0 = (c0 & 3) * 8;
  int r1 = c1 >> 2, o1 = (c1 & 3) * 8;

  f32x4 acc[2][4][4] = {};
  // stage K-step kn into buffer buf: 6 loads/thread (2 A + 4 B)
  auto STAGE = [&](int kn, int buf) {
    stage16(Abase + (size_t)r0*NPAD + kn + o0, As + buf*4096 + c0*8);
    stage16(Abase + (size_t)r1*NPAD + kn + o1, As + buf*4096 + c1*8);
#pragma unroll
    for (int q = 0; q < 4; ++q) {
      int c = q*256 + tid;               // 0..1023
      int bb = c >> 9, cc = c & 511;
      int rr = cc >> 2, j = (cc & 3)*8;
      stage16(Bbase + (size_t)rr*MT + bb*NPAD + kn + j, Bs + buf*8192 + c*8);
    }
  };
  STAGE(0, 0);
  STAGE(32, 1);
  for (int t = 0; t < 16; ++t) {
    int cur = t % 3;
    if (t < 14) {
      STAGE((t+2)*32, (t+2) % 3);
      asm volatile("s_waitcnt vmcnt(12)" ::: "memory");   // step-t's 6 retired
    } else if (t == 14) {
      asm volatile("s_waitcnt vmcnt(6)" ::: "memory");
    } else {
      asm volatile("s_waitcnt vmcnt(0)" ::: "memory");
    }
    __builtin_amdgcn_s_barrier();
    __builtin_amdgcn_sched_barrier(0);
    short8 af[4], bfv[2][4];
#pragma unroll
    for (int i = 0; i < 4; ++i)
      af[i] = *(const short8*)(As + cur*4096 + (wm + i*16 + l15)*32 + quad*8);
#pragma unroll
    for (int bb = 0; bb < 2; ++bb)
#pragma unroll
      for (int i = 0; i < 4; ++i)
        bfv[bb][i] = *(const short8*)(Bs + cur*8192 + bb*4096 + (wn + i*16 + l15)*32 + quad*8);
#pragma unroll
    for (int bb = 0; bb < 2; ++bb)
#pragma unroll
      for (int mi = 0; mi < 4; ++mi)
#pragma unroll
        for (int ni = 0; ni < 4; ++ni)
          mfma16(acc[bb][mi][ni], af[mi], bfv[bb][ni]);
    __builtin_amdgcn_sched_barrier(0);
    __builtin_amdgcn_s_barrier();
  }
  asm volatile("s_nop 7\n\ts_nop 7" ::);
  // BN stat partials over both batches (pad rows contribute exactly 0)
  float ps[4] = {0,0,0,0}, pq[4] = {0,0,0,0};
#pragma unroll
  for (int bb = 0; bb < 2; ++bb)
#pragma unroll
    for (int ni = 0; ni < 4; ++ni)
#pragma unroll
      for (int mi = 0; mi < 4; ++mi)
#pragma unroll
        for (int r = 0; r < 4; ++r) {
          float v = acc[bb][mi][ni][r];
          ps[ni] += v; pq[ni] += v*v;
        }
  // transposed epilogue, one batch at a time (scratch reuses smem)
  int noff = (tid & 15)*8;
#pragma unroll
  for (int bb = 0; bb < 2; ++bb) {
#pragma unroll
    for (int mi = 0; mi < 4; ++mi) {
      int ml = wm + mi*16 + quad*4;
#pragma unroll
      for (int ni = 0; ni < 4; ++ni) {
        int nl = wn + ni*16 + l15;
#pragma unroll
        for (int r = 0; r < 4; ++r)
          smem[(ml + r)*EPITCH + nl] = f2bf(acc[bb][mi][ni][r]);
      }
    }
    __syncthreads();
    unsigned short* Xrow = Xbo + (size_t)(b + bb)*NPAD*HH;
#pragma unroll
    for (int j = 0; j < 8; ++j) {
      int rr = (tid >> 4) + j*16;
      int node = row0 + rr;
      if (node < NNODES) {
        uint4 d = *(const uint4*)(smem + rr*EPITCH + noff);
        *(uint4*)(Xrow + (size_t)node*HH + col0 + noff) = d;
      }
    }
    __syncthreads();
  }
  float* red = (float*)smem;
  red[tid] = 0.f;
  __syncthreads();
#pragma unroll
  for (int ni = 0; ni < 4; ++ni) {
    int cl = wn + ni*16 + l15;
    atomicAdd(&red[cl], ps[ni]);
    atomicAdd(&red[128+cl], pq[ni]);
  }
  __syncthreads();
  if (tid < 128) atomicAdd(&sums[col0+tid], red[tid]);
  else atomicAdd(&ssqs[col0+tid-128], red[tid]);
}

__global__ void finalize_kernel(const float* __restrict__ sums, const float* __restrict__ ssqs,
                                const float* __restrict__ gamma, const float* __restrict__ beta,
                                float* __restrict__ scale, float* __restrict__ shift) {
  int h = threadIdx.x;
  const float cnt = (float)MROWS;
  float mean = sums[h] / cnt;
  float var  = ssqs[h] / cnt - mean*mean;
  float scl  = gamma[h] * rsqrtf(var + 1e-5f);
  scale[h] = scl; shift[h] = beta[h] - mean*scl;
}

// final BN+ELU: read bf16 Xb (raw layer-3 pre-BN), write fp32 d_out
__global__ __launch_bounds__(256) void bnout_kernel(
    const unsigned short* __restrict__ Xb, const float* __restrict__ scale,
    const float* __restrict__ shift, float* __restrict__ O) {
  int idx = blockIdx.x*256 + threadIdx.x;   // over MT*64
  int row = idx >> 6, h0 = (idx & 63)*4;
  int b = row >> 9, n = row & (NPAD-1);
  if (n >= NNODES) return;
  union { unsigned short u[4]; uint2 d; } v;
  v.d = *(const uint2*)(Xb + (size_t)row*HH + h0);
  float4 sc = *(const float4*)(scale + h0);
  float4 sh = *(const float4*)(shift + h0);
  float4 o;
  o.x = elu(bf2f(v.u[0])*sc.x + sh.x);
  o.y = elu(bf2f(v.u[1])*sc.y + sh.y);
  o.z = elu(bf2f(v.u[2])*sc.z + sh.z);
  o.w = elu(bf2f(v.u[3])*sc.w + sh.w);
  *(float4*)(O + ((size_t)(b*NNODES + n)*HH + h0)) = o;
}

extern "C" void kernel_launch(void* const* d_in, const int* in_sizes, int n_in,
                              void* d_out, int out_size, void* d_ws, size_t ws_size,
                              hipStream_t stream) {
  const float* sensor = (const float*)d_in[0];
  const float* base   = (const float*)d_in[1];
  const int*   eidx   = (const int*)d_in[2];
  const float* W1 = (const float*)d_in[3];
  const float* g1 = (const float*)d_in[5];
  const float* be1= (const float*)d_in[6];
  const float* W2 = (const float*)d_in[7];
  const float* g2 = (const float*)d_in[9];
  const float* be2= (const float*)d_in[10];
  const float* W3 = (const float*)d_in[11];
  const float* g3 = (const float*)d_in[13];
  const float* be3= (const float*)d_in[14];

  char* ws = (char*)d_ws;
  // ---- zeroed region [0, 16384) ----
  int*   deg    = (int*)(ws + 0);
  float* sum2   = (float*)(ws + 2048);
  float* ssq2   = (float*)(ws + 3072);
  float* sum3   = (float*)(ws + 4096);
  float* ssq3   = (float*)(ws + 5120);
  float* cbuf   = (float*)(ws + 6144);
  int*   cursor = (int*)(ws + 8192);
  float* sA1    = (float*)(ws + 10496);
  float* sAA1   = (float*)(ws + 11520);
  float* sAc1   = (float*)(ws + 12544);
  float* scp    = (float*)(ws + 13568);
  float* ssA    = (float*)(ws + 13824);
  float* sssA   = (float*)(ws + 14848);
  // ---- end zeroed ----
  float* dinv   = (float*)(ws + 16384);
  int*   rp     = (int*)(ws + 18432);
  int*   colA   = (int*)(ws + 20480);
  float* valA   = (float*)(ws + 40960);
  float* scale1 = (float*)(ws + 61440);
  float* shift1 = (float*)(ws + 62464);
  float* scale3 = (float*)(ws + 65536);
  float* shift3 = (float*)(ws + 66560);
  float* Abuf   = (float*)(ws + 67584);                  // 502*256 f32
  float* hcat   = (float*)(ws + 581632);                 // 628*256 f32
  unsigned short* Wt2 = (unsigned short*)(ws + 1224704); // 256*256 bf16
  unsigned short* Wt3 = (unsigned short*)(ws + 1355776);
  unsigned short* Sd  = (unsigned short*)(ws + 1486848); // 512*512 bf16
  unsigned short* Xb  = (unsigned short*)(ws + 2011136); // MT*256 bf16
  unsigned short* Tt  = (unsigned short*)(ws + 35565568UL); // 256*MT bf16
  // Xp1/Wt1 alias the Tt region: only used before first gemmT3 writes Tt
  unsigned short* Xp1 = (unsigned short*)(ws + 35565568UL);            // 640*1024
  unsigned short* Wt1 = (unsigned short*)(ws + 35565568UL + 1310720);  // 256*1024
  float* out = (float*)d_out;
  float* Sdf = (float*)d_out;   // scratch; d_out rewritten by bnout at the end

  hipMemsetAsync(ws, 0, 16384, stream);
  hipMemsetAsync(d_out, 0, NPAD*NPAD*4, stream);
  deg_kernel<<<(NET+255)/256, 256, 0, stream>>>(eidx, deg);
  scan_kernel<<<1, 512, 0, stream>>>(deg, dinv, rp, cursor);
  fillsdf_kernel<<<(NET+255)/256, 256, 0, stream>>>(eidx, dinv, cursor, colA, valA, Sdf);
  sdcvt_kernel<<<(NPAD*NPAD)/256, 256, 0, stream>>>(Sdf, Sd);
  prep_kernel<<<2036, 256, 0, stream>>>(W1, W2, W3, base, sensor, Wt1, Wt2, Wt3, Xp1, hcat);

  gemm1m_kernel<<<dim3(2, 5, 4), 256, 0, stream>>>(Xp1, Wt1, hcat);
  ac_kernel<<<NNODES, 256, 0, stream>>>(rp, colA, valA, hcat, Abuf, cbuf);
  bn1n_kernel<<<40, 256, 0, stream>>>(Abuf, cbuf, hcat, sA1, sAA1, sAc1, scp, ssA, sssA);
  fin1_kernel<<<1, 256, 0, stream>>>(sA1, sAA1, sAc1, scp, ssA, sssA, g1, be1, scale1, shift1);
  x2_kernel<<<(MT*64)/256, 256, 0, stream>>>(Abuf, cbuf, hcat, scale1, shift1, Xb);

  // layer 2
  gemmT3_kernel<0><<<MT/128, 256, 0, stream>>>(Xb, Wt2, sum2, ssq2, g2, be2, Tt);
  gemmS2_kernel<<<512, 256, 0, stream>>>(Sd, Tt, Xb, sum2, ssq2);
  // layer 3: BN2 finalize+apply fused into pipelined A-staging of gemmT3<1>
  gemmT3_kernel<1><<<MT/128, 256, 0, stream>>>(Xb, Wt3, sum2, ssq2, g2, be2, Tt);
  gemmS2_kernel<<<512, 256, 0, stream>>>(Sd, Tt, Xb, sum3, ssq3);
  finalize_kernel<<<1, 256, 0, stream>>>(sum3, ssq3, g3, be3, scale3, shift3);
  bnout_kernel<<<(MT*64)/256, 256, 0, stream>>>(Xb, scale3, shift3, out);
}